// Round 1
// baseline (654.384 us; speedup 1.0000x reference)
//
#include <hip/hip_runtime.h>
#include <math.h>

#define B_ 8
#define C_ 256
#define N_ 1024
#define NH_ 8
#define HD_ 32

static constexpr size_t QSZ     = (size_t)B_*NH_*N_*HD_;          // 2,097,152 floats
static constexpr size_t OFF_Q   = 0;
static constexpr size_t OFF_K   = QSZ;
static constexpr size_t OFF_V   = 2*QSZ;
static constexpr size_t OFF_E1  = 3*QSZ;
static constexpr size_t OFF_E2  = OFF_E1 + (size_t)NH_*32*32;
static constexpr size_t OFF_SE1 = OFF_E2 + (size_t)NH_*32*32;
static constexpr size_t OFF_SE2 = OFF_SE1 + (size_t)NH_*32;
static constexpr size_t OFF_A2  = OFF_SE2 + (size_t)NH_*32;       // 16B aligned
static constexpr size_t A2S     = 36;                              // 33 used, padded
static constexpr size_t OFF_O   = OFF_A2 + (size_t)B_*NH_*N_*A2S;
// total = OFF_O + B_*N_*C_ = 10,764,800 floats = 41.1 MB of ws

// ---------------------------------------------------------------------------
// Kernel 1: fused QKV projection.
// out[b,n,j] = sum_c x[b,c,n] * W[j,c],  j in [0,768): 0..511 -> Wqk (q,k),
// 512..767 -> Wv.  Scatter into q/k/v buffers laid out (B,NH,N,HD).
// ---------------------------------------------------------------------------
__global__ __launch_bounds__(256) void k_qkv(
    const float* __restrict__ x, const float* __restrict__ Wqk,
    const float* __restrict__ Wv, float* __restrict__ qb,
    float* __restrict__ kb, float* __restrict__ vb)
{
    const int jt = blockIdx.x, nt = blockIdx.y, b = blockIdx.z;
    const int jb = jt*64, nb = nt*64;
    __shared__ float xs[32][68];    // [c][n], stride 68 keeps float4 align
    __shared__ float wsm[64][33];   // [j][c]
    const int tid = threadIdx.x;
    const int tx = tid & 15, ty = tid >> 4;
    float acc[4][4] = {};           // acc[ni][jj]
    const float* xbase = x + (size_t)b*C_*N_;

    for (int c0 = 0; c0 < C_; c0 += 32) {
        {   // stage x tile: 32c x 64n, coalesced along n
            int ci = tid >> 3;
            int nl = (tid & 7) * 8;
            const float* src = xbase + (size_t)(c0+ci)*N_ + nb + nl;
            float4 v0 = ((const float4*)src)[0];
            float4 v1 = ((const float4*)src)[1];
            *(float4*)&xs[ci][nl]   = v0;
            *(float4*)&xs[ci][nl+4] = v1;
        }
        {   // stage W tile: 64j x 32c, coalesced along c
            int jl = tid >> 2;
            int cl = (tid & 3) * 8;
            int jg = jb + jl;
            const float* wrow = (jg < 512) ? (Wqk + (size_t)jg*C_)
                                           : (Wv  + (size_t)(jg-512)*C_);
            float4 w0 = ((const float4*)(wrow + c0 + cl))[0];
            float4 w1 = ((const float4*)(wrow + c0 + cl))[1];
            wsm[jl][cl+0]=w0.x; wsm[jl][cl+1]=w0.y; wsm[jl][cl+2]=w0.z; wsm[jl][cl+3]=w0.w;
            wsm[jl][cl+4]=w1.x; wsm[jl][cl+5]=w1.y; wsm[jl][cl+6]=w1.z; wsm[jl][cl+7]=w1.w;
        }
        __syncthreads();
        #pragma unroll
        for (int ci = 0; ci < 32; ++ci) {
            float4 xv = *(const float4*)&xs[ci][tx*4];
            float xa[4] = {xv.x, xv.y, xv.z, xv.w};
            float wv[4];
            #pragma unroll
            for (int jj = 0; jj < 4; ++jj) wv[jj] = wsm[ty*4+jj][ci];
            #pragma unroll
            for (int ni = 0; ni < 4; ++ni)
                #pragma unroll
                for (int jj = 0; jj < 4; ++jj)
                    acc[ni][jj] = fmaf(xa[ni], wv[jj], acc[ni][jj]);
        }
        __syncthreads();
    }

    #pragma unroll
    for (int jj = 0; jj < 4; ++jj) {
        int jg = jb + ty*4 + jj;
        float* dst; int h, d;
        if (jg < 512) { int s = jg >> 8; h = (jg >> 5) & 7; d = jg & 31; dst = s ? kb : qb; }
        else          { int c2 = jg - 512; h = c2 >> 5; d = c2 & 31; dst = vb; }
        size_t base = (((size_t)b*NH_ + h)*N_)*HD_ + d;
        #pragma unroll
        for (int ni = 0; ni < 4; ++ni) {
            int n = nb + tx*4 + ni;
            dst[base + (size_t)n*HD_] = acc[ni][jj];
        }
    }
}

// ---------------------------------------------------------------------------
// Kernel 2: positional factor tables per head.
// L[h,n,m] = wx*dx + wy*dy + wd*(dx^2+dy^2) + bpos  with dx=cm-cn, dy=rm-rn.
// Separable: E1[h,cn,cm] = exp(wx*dx+wd*dx^2+b - rowmax), E2[h,rn,rm] likewise.
// ---------------------------------------------------------------------------
__global__ __launch_bounds__(1024) void k_pos_tables(
    const float* __restrict__ Wpos, const float* __restrict__ bpos,
    float* __restrict__ e1, float* __restrict__ e2,
    float* __restrict__ se1, float* __restrict__ se2)
{
    const int h = blockIdx.x;
    const int tid = threadIdx.x;
    const int i = tid >> 5, j = tid & 31;
    const float wx = Wpos[h*3+0], wy = Wpos[h*3+1], wd = Wpos[h*3+2], bp = bpos[h];
    __shared__ float sh[2][32][33];
    float fmx = -1e30f, gmx = -1e30f;
    for (int jp = 0; jp < 32; ++jp) {
        float dx = (float)(jp - i);
        float q2 = wd*dx*dx;
        fmx = fmaxf(fmx, wx*dx + q2 + bp);
        gmx = fmaxf(gmx, wy*dx + q2);
    }
    float dx = (float)(j - i);
    float q2 = wd*dx*dx;
    float fv = __expf(wx*dx + q2 + bp - fmx);
    float gv = __expf(wy*dx + q2 - gmx);
    e1[h*1024 + i*32 + j] = fv;
    e2[h*1024 + i*32 + j] = gv;
    sh[0][i][j] = fv; sh[1][i][j] = gv;
    __syncthreads();
    if (tid < 32) {
        float s1 = 0.f, s2 = 0.f;
        for (int jp = 0; jp < 32; ++jp) { s1 += sh[0][tid][jp]; s2 += sh[1][tid][jp]; }
        se1[h*32+tid] = s1; se2[h*32+tid] = s2;
    }
}

// ---------------------------------------------------------------------------
// Kernel 3: positional attention @ V via separable contraction.
// T1[rn,cm,d] = sum_rm E2[rn,rm] * V[rm*32+cm, d]   (d=32 -> mask channel)
// A2[n=rn*32+cn, d] = sum_cm E1[cn,cm] * T1[rn,cm,d]
// ---------------------------------------------------------------------------
__global__ __launch_bounds__(256) void k_pos_apply(
    const float* __restrict__ vb, const float* __restrict__ mask,
    const float* __restrict__ e1, const float* __restrict__ e2,
    float* __restrict__ a2)
{
    const int rg = blockIdx.x, h = blockIdx.y, b = blockIdx.z;
    const int tid = threadIdx.x;
    __shared__ float t1[8*32*34];
    const float* vbh = vb + (((size_t)b*NH_ + h)*N_)*HD_;
    const float* mb  = mask + (size_t)b*N_;
    const float* e1h = e1 + h*1024;
    const float* e2h = e2 + h*1024;

    #pragma unroll 1
    for (int k = 0; k < 33; ++k) {
        int oi = k*256 + tid;                 // 0..8447
        int d  = oi % 33;
        int cm = (oi/33) & 31;
        int rl = oi / (33*32);
        const float* e2row = e2h + (rg*8+rl)*32;
        float s = 0.f;
        if (d < 32) {
            for (int rm = 0; rm < 32; ++rm)
                s = fmaf(e2row[rm], vbh[(size_t)(rm*32+cm)*HD_ + d], s);
        } else {
            for (int rm = 0; rm < 32; ++rm)
                s = fmaf(e2row[rm], mb[rm*32+cm], s);
        }
        t1[(rl*32+cm)*34 + d] = s;
    }
    __syncthreads();
    #pragma unroll 1
    for (int k = 0; k < 33; ++k) {
        int oi = k*256 + tid;
        int d  = oi % 33;
        int cn = (oi/33) & 31;
        int rl = oi / (33*32);
        const float* e1row = e1h + cn*32;
        const float* t1row = &t1[(rl*32)*34 + d];
        float s = 0.f;
        for (int cm = 0; cm < 32; ++cm)
            s = fmaf(e1row[cm], t1row[cm*34], s);
        int n = (rg*8+rl)*32 + cn;
        a2[(((size_t)b*NH_ + h)*N_ + n)*A2S + d] = s;
    }
}

// ---------------------------------------------------------------------------
// Kernel 4: main attention (patch part) + combine with pos part.
// One thread = (row n, m-quarter). K/V read via wave-uniform broadcast loads.
// Patch logits are small => no max subtraction needed for exp.
// ---------------------------------------------------------------------------
__global__ __launch_bounds__(256) void k_attn(
    const float* __restrict__ qb, const float* __restrict__ kb,
    const float* __restrict__ vb, const float* __restrict__ mask,
    const float* __restrict__ a2, const float* __restrict__ se1,
    const float* __restrict__ se2, const float* __restrict__ gating,
    float* __restrict__ ob)
{
    const int tile = blockIdx.x, h = blockIdx.y, b = blockIdx.z;
    const int tid = threadIdx.x;
    const int lane = tid & 63;
    const int part = tid >> 6;
    const int n = tile*64 + lane;
    const size_t bh = (size_t)b*NH_ + h;
    const float* qp = qb + (bh*N_ + n)*HD_;
    const float* kh = kb + bh*N_*HD_;
    const float* vh = vb + bh*N_*HD_;
    const float* mb = mask + (size_t)b*N_;

    float4 qr[8];
    #pragma unroll
    for (int d = 0; d < 8; ++d) qr[d] = ((const float4*)qp)[d];
    float4 a4[8];
    #pragma unroll
    for (int d = 0; d < 8; ++d) a4[d] = make_float4(0.f,0.f,0.f,0.f);
    float zs = 0.f, z1m = 0.f;
    const float scale = 0.1767766952966369f;   // 1/sqrt(32)

    const int m0 = part*256;
    for (int m = m0; m < m0 + 256; ++m) {
        const float4* kp = (const float4*)(kh + (size_t)m*HD_);
        const float4* vp = (const float4*)(vh + (size_t)m*HD_);
        float s0=0.f, s1=0.f, s2=0.f, s3=0.f;
        #pragma unroll
        for (int d = 0; d < 8; ++d) {
            float4 kv = kp[d];
            s0 = fmaf(qr[d].x, kv.x, s0);
            s1 = fmaf(qr[d].y, kv.y, s1);
            s2 = fmaf(qr[d].z, kv.z, s2);
            s3 = fmaf(qr[d].w, kv.w, s3);
        }
        float e  = __expf(((s0+s1)+(s2+s3)) * scale);
        float em = e * mb[m];
        zs += e; z1m += em;
        #pragma unroll
        for (int d = 0; d < 8; ++d) {
            float4 vv = vp[d];
            a4[d].x = fmaf(em, vv.x, a4[d].x);
            a4[d].y = fmaf(em, vv.y, a4[d].y);
            a4[d].z = fmaf(em, vv.z, a4[d].z);
            a4[d].w = fmaf(em, vv.w, a4[d].w);
        }
    }

    __shared__ float red[256][36];
    #pragma unroll
    for (int d = 0; d < 8; ++d) *(float4*)&red[tid][d*4] = a4[d];
    red[tid][32] = zs; red[tid][33] = z1m;
    __syncthreads();

    if (tid < 64) {
        float4 t4[8];
        #pragma unroll
        for (int d = 0; d < 8; ++d) t4[d] = *(float4*)&red[tid][d*4];
        float tzs = red[tid][32], tz1 = red[tid][33];
        #pragma unroll
        for (int p = 1; p < 4; ++p) {
            int r = p*64 + tid;
            #pragma unroll
            for (int d = 0; d < 8; ++d) {
                float4 u = *(float4*)&red[r][d*4];
                t4[d].x += u.x; t4[d].y += u.y; t4[d].z += u.z; t4[d].w += u.w;
            }
            tzs += red[r][32]; tz1 += red[r][33];
        }
        const float* a2p = a2 + (bh*N_ + n)*A2S;
        float z2m = a2p[32];
        float zp  = se1[h*32 + (n & 31)] * se2[h*32 + (n >> 5)];
        float g   = 1.f / (1.f + __expf(-gating[h]));
        float w1  = (1.f - g) / tzs;
        float w2  = g / zp;
        float inv = 1.f / (w1*tz1 + w2*z2m);
        float* op = ob + ((size_t)b*N_ + n)*C_ + h*HD_;
        #pragma unroll
        for (int d = 0; d < 8; ++d) {
            float4 av = *(const float4*)&a2p[d*4];
            float4 o4;
            o4.x = (w1*t4[d].x + w2*av.x) * inv;
            o4.y = (w1*t4[d].y + w2*av.y) * inv;
            o4.z = (w1*t4[d].z + w2*av.z) * inv;
            o4.w = (w1*t4[d].w + w2*av.w) * inv;
            ((float4*)op)[d] = o4;
        }
    }
}

// ---------------------------------------------------------------------------
// Kernel 5: output projection + bias, transposed write to (B,C,N).
// out[b,c,n] = sum_c2 o[b,n,c2] * Wproj[c,c2] + bproj[c]
// ---------------------------------------------------------------------------
__global__ __launch_bounds__(256) void k_proj(
    const float* __restrict__ ob, const float* __restrict__ Wp,
    const float* __restrict__ bp, float* __restrict__ out)
{
    const int ct = blockIdx.x, nt = blockIdx.y, b = blockIdx.z;
    const int cb = ct*64, nb = nt*64;
    const int tid = threadIdx.x;
    const int tx = tid & 15, ty = tid >> 4;
    __shared__ float os[64][33];
    __shared__ float wt[64][33];
    float acc[4][4] = {};   // acc[cj][ni]

    for (int c0 = 0; c0 < C_; c0 += 32) {
        int rl = tid >> 2;
        int cl = (tid & 3) * 8;
        {
            const float* src = ob + ((size_t)b*N_ + nb + rl)*C_ + c0 + cl;
            float4 v0 = ((const float4*)src)[0];
            float4 v1 = ((const float4*)src)[1];
            os[rl][cl+0]=v0.x; os[rl][cl+1]=v0.y; os[rl][cl+2]=v0.z; os[rl][cl+3]=v0.w;
            os[rl][cl+4]=v1.x; os[rl][cl+5]=v1.y; os[rl][cl+6]=v1.z; os[rl][cl+7]=v1.w;
            const float* wsrc = Wp + (size_t)(cb + rl)*C_ + c0 + cl;
            float4 w0 = ((const float4*)wsrc)[0];
            float4 w1 = ((const float4*)wsrc)[1];
            wt[rl][cl+0]=w0.x; wt[rl][cl+1]=w0.y; wt[rl][cl+2]=w0.z; wt[rl][cl+3]=w0.w;
            wt[rl][cl+4]=w1.x; wt[rl][cl+5]=w1.y; wt[rl][cl+6]=w1.z; wt[rl][cl+7]=w1.w;
        }
        __syncthreads();
        #pragma unroll
        for (int c2 = 0; c2 < 32; ++c2) {
            float ov[4], wv[4];
            #pragma unroll
            for (int ni = 0; ni < 4; ++ni) ov[ni] = os[tx*4+ni][c2];
            #pragma unroll
            for (int cj = 0; cj < 4; ++cj) wv[cj] = wt[ty*4+cj][c2];
            #pragma unroll
            for (int cj = 0; cj < 4; ++cj)
                #pragma unroll
                for (int ni = 0; ni < 4; ++ni)
                    acc[cj][ni] = fmaf(wv[cj], ov[ni], acc[cj][ni]);
        }
        __syncthreads();
    }

    #pragma unroll
    for (int cj = 0; cj < 4; ++cj) {
        float bv = bp[cb + ty*4 + cj];
        #pragma unroll
        for (int ni = 0; ni < 4; ++ni)
            out[((size_t)b*C_ + cb + ty*4 + cj)*N_ + nb + tx*4 + ni] = acc[cj][ni] + bv;
    }
}

// ---------------------------------------------------------------------------
extern "C" void kernel_launch(void* const* d_in, const int* in_sizes, int n_in,
                              void* d_out, int out_size, void* d_ws, size_t ws_size,
                              hipStream_t stream)
{
    (void)in_sizes; (void)n_in; (void)out_size; (void)ws_size;
    const float* x      = (const float*)d_in[0];
    const float* mask   = (const float*)d_in[1];
    const float* Wqk    = (const float*)d_in[2];
    const float* Wv     = (const float*)d_in[3];
    const float* Wproj  = (const float*)d_in[4];
    const float* bproj  = (const float*)d_in[5];
    const float* Wpos   = (const float*)d_in[6];
    const float* bpos   = (const float*)d_in[7];
    const float* gating = (const float*)d_in[8];
    float* out = (float*)d_out;
    float* w   = (float*)d_ws;

    float* qb   = w + OFF_Q;
    float* kbuf = w + OFF_K;
    float* vbuf = w + OFF_V;
    float* e1   = w + OFF_E1;
    float* e2   = w + OFF_E2;
    float* se1  = w + OFF_SE1;
    float* se2  = w + OFF_SE2;
    float* a2   = w + OFF_A2;
    float* obuf = w + OFF_O;

    k_qkv<<<dim3(12,16,8), dim3(256), 0, stream>>>(x, Wqk, Wv, qb, kbuf, vbuf);
    k_pos_tables<<<dim3(8), dim3(1024), 0, stream>>>(Wpos, bpos, e1, e2, se1, se2);
    k_pos_apply<<<dim3(4,8,8), dim3(256), 0, stream>>>(vbuf, mask, e1, e2, a2);
    k_attn<<<dim3(16,8,8), dim3(256), 0, stream>>>(qb, kbuf, vbuf, mask, a2, se1, se2, gating, obuf);
    k_proj<<<dim3(4,16,8), dim3(256), 0, stream>>>(obuf, Wproj, bproj, out);
}

// Round 2
// 200.564 us; speedup vs baseline: 3.2627x; 3.2627x over previous
//
#include <hip/hip_runtime.h>
#include <hip/hip_bf16.h>
#include <math.h>

#define B_ 8
#define C_ 256
#define N_ 1024
#define NH_ 8
#define HD_ 32

typedef __attribute__((ext_vector_type(8))) short bf16x8;
typedef __attribute__((ext_vector_type(4))) float f32x4;
#define MFMA16(a,b,c) __builtin_amdgcn_mfma_f32_16x16x32_bf16((a),(b),(c),0,0,0)

// ---- workspace byte offsets -------------------------------------------------
static constexpr size_t OFF_VB  = 0;                         // fp32 V [b,h,n,d]   8 MB
static constexpr size_t OFF_QBF = 8388608;                   // bf16 Q [b,h,n,d]   4 MB
static constexpr size_t OFF_KBF = 12582912;                  // bf16 K [b,h,n,d]   4 MB
static constexpr size_t OFF_VT  = 16777216;                  // bf16 V^T [b,h,d,n] 4 MB
static constexpr size_t OFF_E1  = 20971520;                  // 32 KB
static constexpr size_t OFF_E2  = 21004288;                  // 32 KB
static constexpr size_t OFF_SE1 = 21037056;                  // 1 KB
static constexpr size_t OFF_SE2 = 21038080;                  // 1 KB
static constexpr size_t OFF_A2  = 21039104;                  // fp32 [b,h,n,36] 9.4 MB
static constexpr size_t A2S     = 36;
static constexpr size_t OFF_O   = 30476288;                  // fp32 [b,n,c] 8 MB
// end = 38,864,896 bytes

// ---------------------------------------------------------------------------
// Kernel 1: fused QKV projection -> bf16 Q,K ; bf16 V^T ; fp32 V
// ---------------------------------------------------------------------------
__global__ __launch_bounds__(256) void k_qkv(
    const float* __restrict__ x, const float* __restrict__ Wqk,
    const float* __restrict__ Wv, __hip_bfloat16* __restrict__ qbf,
    __hip_bfloat16* __restrict__ kbf, __hip_bfloat16* __restrict__ vt,
    float* __restrict__ vbuf)
{
    const int jt = blockIdx.x, nt = blockIdx.y, b = blockIdx.z;
    const int jb = jt*64, nb = nt*64;
    __shared__ float xs[32][68];
    __shared__ float wsm[64][33];
    const int tid = threadIdx.x;
    const int tx = tid & 15, ty = tid >> 4;
    float acc[4][4] = {};
    const float* xbase = x + (size_t)b*C_*N_;

    for (int c0 = 0; c0 < C_; c0 += 32) {
        {
            int ci = tid >> 3;
            int nl = (tid & 7) * 8;
            const float* src = xbase + (size_t)(c0+ci)*N_ + nb + nl;
            float4 v0 = ((const float4*)src)[0];
            float4 v1 = ((const float4*)src)[1];
            *(float4*)&xs[ci][nl]   = v0;
            *(float4*)&xs[ci][nl+4] = v1;
        }
        {
            int jl = tid >> 2;
            int cl = (tid & 3) * 8;
            int jg = jb + jl;
            const float* wrow = (jg < 512) ? (Wqk + (size_t)jg*C_)
                                           : (Wv  + (size_t)(jg-512)*C_);
            float4 w0 = ((const float4*)(wrow + c0 + cl))[0];
            float4 w1 = ((const float4*)(wrow + c0 + cl))[1];
            wsm[jl][cl+0]=w0.x; wsm[jl][cl+1]=w0.y; wsm[jl][cl+2]=w0.z; wsm[jl][cl+3]=w0.w;
            wsm[jl][cl+4]=w1.x; wsm[jl][cl+5]=w1.y; wsm[jl][cl+6]=w1.z; wsm[jl][cl+7]=w1.w;
        }
        __syncthreads();
        #pragma unroll
        for (int ci = 0; ci < 32; ++ci) {
            float4 xv = *(const float4*)&xs[ci][tx*4];
            float xa[4] = {xv.x, xv.y, xv.z, xv.w};
            float wv[4];
            #pragma unroll
            for (int jj = 0; jj < 4; ++jj) wv[jj] = wsm[ty*4+jj][ci];
            #pragma unroll
            for (int ni = 0; ni < 4; ++ni)
                #pragma unroll
                for (int jj = 0; jj < 4; ++jj)
                    acc[ni][jj] = fmaf(xa[ni], wv[jj], acc[ni][jj]);
        }
        __syncthreads();
    }

    #pragma unroll
    for (int jj = 0; jj < 4; ++jj) {
        int jg = jb + ty*4 + jj;
        if (jg < 512) {
            int s = jg >> 8, hh = (jg >> 5) & 7, d = jg & 31;
            __hip_bfloat16* dst = s ? kbf : qbf;
            size_t base = (((size_t)b*NH_ + hh)*N_)*HD_ + d;
            #pragma unroll
            for (int ni = 0; ni < 4; ++ni) {
                int n = nb + tx*4 + ni;
                dst[base + (size_t)n*HD_] = __float2bfloat16(acc[ni][jj]);
            }
        } else {
            int c2 = jg - 512, hh = c2 >> 5, d = c2 & 31;
            size_t bh = (size_t)b*NH_ + hh;
            #pragma unroll
            for (int ni = 0; ni < 4; ++ni) {
                int n = nb + tx*4 + ni;
                float a = acc[ni][jj];
                vbuf[(bh*N_ + n)*HD_ + d] = a;
                vt[(bh*HD_ + d)*N_ + n] = __float2bfloat16(a);
            }
        }
    }
}

// ---------------------------------------------------------------------------
// Kernel 2: positional factor tables per head (separable exp factors).
// ---------------------------------------------------------------------------
__global__ __launch_bounds__(1024) void k_pos_tables(
    const float* __restrict__ Wpos, const float* __restrict__ bpos,
    float* __restrict__ e1, float* __restrict__ e2,
    float* __restrict__ se1, float* __restrict__ se2)
{
    const int h = blockIdx.x;
    const int tid = threadIdx.x;
    const int i = tid >> 5, j = tid & 31;
    const float wx = Wpos[h*3+0], wy = Wpos[h*3+1], wd = Wpos[h*3+2], bp = bpos[h];
    __shared__ float sh[2][32][33];
    float fmx = -1e30f, gmx = -1e30f;
    for (int jp = 0; jp < 32; ++jp) {
        float dx = (float)(jp - i);
        float q2 = wd*dx*dx;
        fmx = fmaxf(fmx, wx*dx + q2 + bp);
        gmx = fmaxf(gmx, wy*dx + q2);
    }
    float dx = (float)(j - i);
    float q2 = wd*dx*dx;
    float fv = __expf(wx*dx + q2 + bp - fmx);
    float gv = __expf(wy*dx + q2 - gmx);
    e1[h*1024 + i*32 + j] = fv;
    e2[h*1024 + i*32 + j] = gv;
    sh[0][i][j] = fv; sh[1][i][j] = gv;
    __syncthreads();
    if (tid < 32) {
        float s1 = 0.f, s2 = 0.f;
        for (int jp = 0; jp < 32; ++jp) { s1 += sh[0][tid][jp]; s2 += sh[1][tid][jp]; }
        se1[h*32+tid] = s1; se2[h*32+tid] = s2;
    }
}

// ---------------------------------------------------------------------------
// Kernel 3: positional attention @ V via separable contraction (fp32 V).
// ---------------------------------------------------------------------------
__global__ __launch_bounds__(256) void k_pos_apply(
    const float* __restrict__ vb, const float* __restrict__ mask,
    const float* __restrict__ e1, const float* __restrict__ e2,
    float* __restrict__ a2)
{
    const int rg = blockIdx.x, h = blockIdx.y, b = blockIdx.z;
    const int tid = threadIdx.x;
    __shared__ float t1[8*32*34];
    const float* vbh = vb + (((size_t)b*NH_ + h)*N_)*HD_;
    const float* mb  = mask + (size_t)b*N_;
    const float* e1h = e1 + h*1024;
    const float* e2h = e2 + h*1024;

    #pragma unroll 1
    for (int k = 0; k < 33; ++k) {
        int oi = k*256 + tid;
        int d  = oi % 33;
        int cm = (oi/33) & 31;
        int rl = oi / (33*32);
        const float* e2row = e2h + (rg*8+rl)*32;
        float s = 0.f;
        if (d < 32) {
            for (int rm = 0; rm < 32; ++rm)
                s = fmaf(e2row[rm], vbh[(size_t)(rm*32+cm)*HD_ + d], s);
        } else {
            for (int rm = 0; rm < 32; ++rm)
                s = fmaf(e2row[rm], mb[rm*32+cm], s);
        }
        t1[(rl*32+cm)*34 + d] = s;
    }
    __syncthreads();
    #pragma unroll 1
    for (int k = 0; k < 33; ++k) {
        int oi = k*256 + tid;
        int d  = oi % 33;
        int cn = (oi/33) & 31;
        int rl = oi / (33*32);
        const float* e1row = e1h + cn*32;
        const float* t1row = &t1[(rl*32)*34 + d];
        float s = 0.f;
        for (int cm = 0; cm < 32; ++cm)
            s = fmaf(e1row[cm], t1row[cm*34], s);
        int n = (rg*8+rl)*32 + cn;
        a2[(((size_t)b*NH_ + h)*N_ + n)*A2S + d] = s;
    }
}

// ---------------------------------------------------------------------------
// Kernel 4: MFMA patch attention + combine.
// One wave = 16 Q-rows. All A/B fragments loaded straight from global
// (coalesced 16B/lane, L2-resident). P round-trips through per-wave LDS
// (stride 40 shorts -> 16B aligned, <=2-way bank conflicts). No barriers.
// ---------------------------------------------------------------------------
__global__ __launch_bounds__(256, 4) void k_attn_mfma(
    const __hip_bfloat16* __restrict__ qbf, const __hip_bfloat16* __restrict__ kbf,
    const __hip_bfloat16* __restrict__ vt, const float* __restrict__ mask,
    const float* __restrict__ a2, const float* __restrict__ se1,
    const float* __restrict__ se2, const float* __restrict__ gating,
    float* __restrict__ ob)
{
    const int h = blockIdx.y, b = blockIdx.z;
    const int tid = threadIdx.x;
    const int w = tid >> 6, L = tid & 63;
    const int lo = L & 15, g = L >> 4;
    const int n0 = blockIdx.x * 64 + w * 16;
    const size_t bh = (size_t)b*NH_ + h;
    const __hip_bfloat16* qh = qbf + bh*(size_t)N_*HD_;
    const __hip_bfloat16* kh = kbf + bh*(size_t)N_*HD_;
    const __hip_bfloat16* vh = vt  + bh*(size_t)HD_*N_;
    const float* mb = mask + (size_t)b*N_;

    __shared__ __hip_bfloat16 plds_all[4][16*40];
    __hip_bfloat16* plds = plds_all[w];

    // Q A-fragment: row = lo, k-chunk = 8*g  (one MFMA covers full hd=32)
    bf16x8 qf = *(const bf16x8*)(qh + (size_t)(n0 + lo)*HD_ + 8*g);

    const __hip_bfloat16* kbase = kh + lo*HD_ + 8*g;     // + m0*HD_ per tile
    const __hip_bfloat16* vbase = vh + (size_t)lo*N_ + 8*g;  // + m0 per tile

    const f32x4 Z = {0.f, 0.f, 0.f, 0.f};
    f32x4 O0 = Z, O1 = Z;
    float zs[4] = {0.f,0.f,0.f,0.f}, z1[4] = {0.f,0.f,0.f,0.f};
    const float SC = 0.1767766952966369f;   // 1/sqrt(32)

    bf16x8 kfa = *(const bf16x8*)(kbase);
    bf16x8 kfb = *(const bf16x8*)(kbase + 16*HD_);
    bf16x8 vfa = *(const bf16x8*)(vbase);
    bf16x8 vfb = *(const bf16x8*)(vbase + 16*N_);
    float ma0 = mb[lo], ma1 = mb[lo + 16];

    for (int mt = 0; mt < 32; ++mt) {
        f32x4 s0 = MFMA16(qf, kfa, Z);
        f32x4 s1 = MFMA16(qf, kfb, Z);
        const int m1 = (mt < 31 ? mt + 1 : mt) * 32;
        bf16x8 nka = *(const bf16x8*)(kbase + (size_t)m1*HD_);
        bf16x8 nkb = *(const bf16x8*)(kbase + (size_t)m1*HD_ + 16*HD_);
        bf16x8 nva = *(const bf16x8*)(vbase + m1);
        bf16x8 nvb = *(const bf16x8*)(vbase + m1 + 16*N_);
        float nm0 = mb[m1 + lo], nm1 = mb[m1 + lo + 16];
        #pragma unroll
        for (int j = 0; j < 4; ++j) {
            float e0  = __expf(s0[j] * SC);
            float e1v = __expf(s1[j] * SC);
            zs[j] += e0 + e1v;
            float p0 = e0 * ma0, p1 = e1v * ma1;
            z1[j] += p0 + p1;
            int r = 4*g + j;
            plds[r*40 + lo]      = __float2bfloat16(p0);
            plds[r*40 + 16 + lo] = __float2bfloat16(p1);
        }
        // P A-fragment: row = lo, k-chunk (m-local) = 8*g
        bf16x8 pa = *(const bf16x8*)(plds + lo*40 + 8*g);
        O0 = MFMA16(pa, vfa, O0);
        O1 = MFMA16(pa, vfb, O1);
        kfa = nka; kfb = nkb; vfa = nva; vfb = nvb; ma0 = nm0; ma1 = nm1;
    }

    const float gs = 1.f / (1.f + __expf(-gating[h]));
    #pragma unroll
    for (int j = 0; j < 4; ++j) {
        float tzs = zs[j], tz1 = z1[j];
        #pragma unroll
        for (int msk = 1; msk < 16; msk <<= 1) {
            tzs += __shfl_xor(tzs, msk);
            tz1 += __shfl_xor(tz1, msk);
        }
        const int n = n0 + 4*g + j;
        const float* a2p = a2 + (bh*N_ + n)*A2S;
        float z2m = a2p[32];
        float zp  = se1[h*32 + (n & 31)] * se2[h*32 + (n >> 5)];
        float w1  = (1.f - gs) / tzs;
        float w2  = gs / zp;
        float inv = 1.f / (w1*tz1 + w2*z2m);
        float o0 = (w1*O0[j] + w2*a2p[lo])      * inv;
        float o1 = (w1*O1[j] + w2*a2p[16 + lo]) * inv;
        float* op = ob + ((size_t)b*N_ + n)*C_ + h*HD_;
        op[lo]      = o0;
        op[16 + lo] = o1;
    }
}

// ---------------------------------------------------------------------------
// Kernel 5: output projection + bias, transposed write to (B,C,N).
// ---------------------------------------------------------------------------
__global__ __launch_bounds__(256) void k_proj(
    const float* __restrict__ ob, const float* __restrict__ Wp,
    const float* __restrict__ bp, float* __restrict__ out)
{
    const int ct = blockIdx.x, nt = blockIdx.y, b = blockIdx.z;
    const int cb = ct*64, nb = nt*64;
    const int tid = threadIdx.x;
    const int tx = tid & 15, ty = tid >> 4;
    __shared__ float os[64][33];
    __shared__ float wt[64][33];
    float acc[4][4] = {};

    for (int c0 = 0; c0 < C_; c0 += 32) {
        int rl = tid >> 2;
        int cl = (tid & 3) * 8;
        {
            const float* src = ob + ((size_t)b*N_ + nb + rl)*C_ + c0 + cl;
            float4 v0 = ((const float4*)src)[0];
            float4 v1 = ((const float4*)src)[1];
            os[rl][cl+0]=v0.x; os[rl][cl+1]=v0.y; os[rl][cl+2]=v0.z; os[rl][cl+3]=v0.w;
            os[rl][cl+4]=v1.x; os[rl][cl+5]=v1.y; os[rl][cl+6]=v1.z; os[rl][cl+7]=v1.w;
            const float* wsrc = Wp + (size_t)(cb + rl)*C_ + c0 + cl;
            float4 w0 = ((const float4*)wsrc)[0];
            float4 w1 = ((const float4*)wsrc)[1];
            wt[rl][cl+0]=w0.x; wt[rl][cl+1]=w0.y; wt[rl][cl+2]=w0.z; wt[rl][cl+3]=w0.w;
            wt[rl][cl+4]=w1.x; wt[rl][cl+5]=w1.y; wt[rl][cl+6]=w1.z; wt[rl][cl+7]=w1.w;
        }
        __syncthreads();
        #pragma unroll
        for (int c2 = 0; c2 < 32; ++c2) {
            float ov[4], wv[4];
            #pragma unroll
            for (int ni = 0; ni < 4; ++ni) ov[ni] = os[tx*4+ni][c2];
            #pragma unroll
            for (int cj = 0; cj < 4; ++cj) wv[cj] = wt[ty*4+cj][c2];
            #pragma unroll
            for (int cj = 0; cj < 4; ++cj)
                #pragma unroll
                for (int ni = 0; ni < 4; ++ni)
                    acc[cj][ni] = fmaf(wv[cj], ov[ni], acc[cj][ni]);
        }
        __syncthreads();
    }

    #pragma unroll
    for (int cj = 0; cj < 4; ++cj) {
        float bv = bp[cb + ty*4 + cj];
        #pragma unroll
        for (int ni = 0; ni < 4; ++ni)
            out[((size_t)b*C_ + cb + ty*4 + cj)*N_ + nb + tx*4 + ni] = acc[cj][ni] + bv;
    }
}

// ---------------------------------------------------------------------------
extern "C" void kernel_launch(void* const* d_in, const int* in_sizes, int n_in,
                              void* d_out, int out_size, void* d_ws, size_t ws_size,
                              hipStream_t stream)
{
    (void)in_sizes; (void)n_in; (void)out_size; (void)ws_size;
    const float* x      = (const float*)d_in[0];
    const float* mask   = (const float*)d_in[1];
    const float* Wqk    = (const float*)d_in[2];
    const float* Wv     = (const float*)d_in[3];
    const float* Wproj  = (const float*)d_in[4];
    const float* bproj  = (const float*)d_in[5];
    const float* Wpos   = (const float*)d_in[6];
    const float* bpos   = (const float*)d_in[7];
    const float* gating = (const float*)d_in[8];
    float* out = (float*)d_out;
    char* w = (char*)d_ws;

    float*          vbuf = (float*)(w + OFF_VB);
    __hip_bfloat16* qbf  = (__hip_bfloat16*)(w + OFF_QBF);
    __hip_bfloat16* kbf  = (__hip_bfloat16*)(w + OFF_KBF);
    __hip_bfloat16* vt   = (__hip_bfloat16*)(w + OFF_VT);
    float*          e1   = (float*)(w + OFF_E1);
    float*          e2   = (float*)(w + OFF_E2);
    float*          se1  = (float*)(w + OFF_SE1);
    float*          se2  = (float*)(w + OFF_SE2);
    float*          a2   = (float*)(w + OFF_A2);
    float*          obuf = (float*)(w + OFF_O);

    k_qkv<<<dim3(12,16,8), dim3(256), 0, stream>>>(x, Wqk, Wv, qbf, kbf, vt, vbuf);
    k_pos_tables<<<dim3(8), dim3(1024), 0, stream>>>(Wpos, bpos, e1, e2, se1, se2);
    k_pos_apply<<<dim3(4,8,8), dim3(256), 0, stream>>>(vbuf, mask, e1, e2, a2);
    k_attn_mfma<<<dim3(16,8,8), dim3(256), 0, stream>>>(qbf, kbf, vt, mask, a2, se1, se2, gating, obuf);
    k_proj<<<dim3(4,16,8), dim3(256), 0, stream>>>(obuf, Wproj, bproj, out);
}

// Round 3
// 149.401 us; speedup vs baseline: 4.3801x; 1.3425x over previous
//
#include <hip/hip_runtime.h>
#include <hip/hip_bf16.h>
#include <math.h>

#define B_ 8
#define C_ 256
#define N_ 1024
#define NH_ 8
#define HD_ 32

typedef __attribute__((ext_vector_type(8))) short bf16x8;
typedef __attribute__((ext_vector_type(4))) float f32x4;
#define MFMA16(a,b,c) __builtin_amdgcn_mfma_f32_16x16x32_bf16((a),(b),(c),0,0,0)

// ---- workspace byte offsets -------------------------------------------------
static constexpr size_t OFF_VB  = 0;                         // fp32 V [b,h,n,d]   8 MB
static constexpr size_t OFF_QBF = 8388608;                   // bf16 Q [b,h,n,d]   4 MB
static constexpr size_t OFF_KBF = 12582912;                  // bf16 K [b,h,n,d]   4 MB
static constexpr size_t OFF_VT  = 16777216;                  // bf16 V^T [b,h,d,n] 4 MB
static constexpr size_t OFF_E1  = 20971520;                  // 32 KB
static constexpr size_t OFF_E2  = 21004288;                  // 32 KB
static constexpr size_t OFF_SE1 = 21037056;                  // 1 KB
static constexpr size_t OFF_SE2 = 21038080;                  // 1 KB
static constexpr size_t OFF_A2  = 21039104;                  // fp32 [b,h,n,36] 9.4 MB
static constexpr size_t A2S     = 36;
static constexpr size_t OFF_O   = 30476288;                  // fp32 [b,n,c] 8 MB
// end = 38,864,896 bytes

// ---------------------------------------------------------------------------
// Kernel 1: fused QKV projection -> bf16 Q,K ; bf16 V^T ; fp32 V
// ---------------------------------------------------------------------------
__global__ __launch_bounds__(256) void k_qkv(
    const float* __restrict__ x, const float* __restrict__ Wqk,
    const float* __restrict__ Wv, __hip_bfloat16* __restrict__ qbf,
    __hip_bfloat16* __restrict__ kbf, __hip_bfloat16* __restrict__ vt,
    float* __restrict__ vbuf)
{
    const int jt = blockIdx.x, nt = blockIdx.y, b = blockIdx.z;
    const int jb = jt*64, nb = nt*64;
    __shared__ float xs[32][68];
    __shared__ float wsm[64][33];
    const int tid = threadIdx.x;
    const int tx = tid & 15, ty = tid >> 4;
    float acc[4][4] = {};
    const float* xbase = x + (size_t)b*C_*N_;

    for (int c0 = 0; c0 < C_; c0 += 32) {
        {
            int ci = tid >> 3;
            int nl = (tid & 7) * 8;
            const float* src = xbase + (size_t)(c0+ci)*N_ + nb + nl;
            float4 v0 = ((const float4*)src)[0];
            float4 v1 = ((const float4*)src)[1];
            *(float4*)&xs[ci][nl]   = v0;
            *(float4*)&xs[ci][nl+4] = v1;
        }
        {
            int jl = tid >> 2;
            int cl = (tid & 3) * 8;
            int jg = jb + jl;
            const float* wrow = (jg < 512) ? (Wqk + (size_t)jg*C_)
                                           : (Wv  + (size_t)(jg-512)*C_);
            float4 w0 = ((const float4*)(wrow + c0 + cl))[0];
            float4 w1 = ((const float4*)(wrow + c0 + cl))[1];
            wsm[jl][cl+0]=w0.x; wsm[jl][cl+1]=w0.y; wsm[jl][cl+2]=w0.z; wsm[jl][cl+3]=w0.w;
            wsm[jl][cl+4]=w1.x; wsm[jl][cl+5]=w1.y; wsm[jl][cl+6]=w1.z; wsm[jl][cl+7]=w1.w;
        }
        __syncthreads();
        #pragma unroll
        for (int ci = 0; ci < 32; ++ci) {
            float4 xv = *(const float4*)&xs[ci][tx*4];
            float xa[4] = {xv.x, xv.y, xv.z, xv.w};
            float wv[4];
            #pragma unroll
            for (int jj = 0; jj < 4; ++jj) wv[jj] = wsm[ty*4+jj][ci];
            #pragma unroll
            for (int ni = 0; ni < 4; ++ni)
                #pragma unroll
                for (int jj = 0; jj < 4; ++jj)
                    acc[ni][jj] = fmaf(xa[ni], wv[jj], acc[ni][jj]);
        }
        __syncthreads();
    }

    #pragma unroll
    for (int jj = 0; jj < 4; ++jj) {
        int jg = jb + ty*4 + jj;
        if (jg < 512) {
            int s = jg >> 8, hh = (jg >> 5) & 7, d = jg & 31;
            __hip_bfloat16* dst = s ? kbf : qbf;
            size_t base = (((size_t)b*NH_ + hh)*N_)*HD_ + d;
            #pragma unroll
            for (int ni = 0; ni < 4; ++ni) {
                int n = nb + tx*4 + ni;
                dst[base + (size_t)n*HD_] = __float2bfloat16(acc[ni][jj]);
            }
        } else {
            int c2 = jg - 512, hh = c2 >> 5, d = c2 & 31;
            size_t bh = (size_t)b*NH_ + hh;
            #pragma unroll
            for (int ni = 0; ni < 4; ++ni) {
                int n = nb + tx*4 + ni;
                float a = acc[ni][jj];
                vbuf[(bh*N_ + n)*HD_ + d] = a;
                vt[(bh*HD_ + d)*N_ + n] = __float2bfloat16(a);
            }
        }
    }
}

// ---------------------------------------------------------------------------
// Kernel 2: positional factor tables per head (separable exp factors).
// ---------------------------------------------------------------------------
__global__ __launch_bounds__(1024) void k_pos_tables(
    const float* __restrict__ Wpos, const float* __restrict__ bpos,
    float* __restrict__ e1, float* __restrict__ e2,
    float* __restrict__ se1, float* __restrict__ se2)
{
    const int h = blockIdx.x;
    const int tid = threadIdx.x;
    const int i = tid >> 5, j = tid & 31;
    const float wx = Wpos[h*3+0], wy = Wpos[h*3+1], wd = Wpos[h*3+2], bp = bpos[h];
    __shared__ float sh[2][32][33];
    float fmx = -1e30f, gmx = -1e30f;
    for (int jp = 0; jp < 32; ++jp) {
        float dx = (float)(jp - i);
        float q2 = wd*dx*dx;
        fmx = fmaxf(fmx, wx*dx + q2 + bp);
        gmx = fmaxf(gmx, wy*dx + q2);
    }
    float dx = (float)(j - i);
    float q2 = wd*dx*dx;
    float fv = __expf(wx*dx + q2 + bp - fmx);
    float gv = __expf(wy*dx + q2 - gmx);
    e1[h*1024 + i*32 + j] = fv;
    e2[h*1024 + i*32 + j] = gv;
    sh[0][i][j] = fv; sh[1][i][j] = gv;
    __syncthreads();
    if (tid < 32) {
        float s1 = 0.f, s2 = 0.f;
        for (int jp = 0; jp < 32; ++jp) { s1 += sh[0][tid][jp]; s2 += sh[1][tid][jp]; }
        se1[h*32+tid] = s1; se2[h*32+tid] = s2;
    }
}

// ---------------------------------------------------------------------------
// Kernel 3 (rewritten): positional attention @ V, fused two-phase per block.
// Block = (rn, h, b).  Phase 1: T1[cm][d] = sum_rm E2[rn,rm]*V[rm*32+cm,d]
// into LDS (coalesced 1KB/wave V reads).  Phase 2: A2[rn*32+cn][d] =
// sum_cm E1[cn,cm]*T1[cm][d] from LDS (padded stride 36 -> conflict-free).
// 2048 blocks -> 8 blocks/CU, latency fully hidden.
// ---------------------------------------------------------------------------
__global__ __launch_bounds__(256) void k_pos_apply(
    const float* __restrict__ vb, const float* __restrict__ mask,
    const float* __restrict__ e1, const float* __restrict__ e2,
    float* __restrict__ a2)
{
    const int rn = blockIdx.x, h = blockIdx.y, b = blockIdx.z;
    const int tid = threadIdx.x;
    const int cm = tid >> 3, dq = tid & 7;       // phase-1/2 thread mapping
    __shared__ float t1[32][36];                 // [cm][d], pad->36
    __shared__ float e1s[32][36];                // [cn][cm], pad->36
    __shared__ float t1m[32];                    // mask channel of T1
    __shared__ float e2s[32];
    const float* vbh = vb + (((size_t)b*NH_ + h)*N_)*HD_;
    const float* mb  = mask + (size_t)b*N_;

    {   // stage E1 (32x32) and E2 row
        int r = tid >> 3, c4 = (tid & 7) * 4;
        *(float4*)&e1s[r][c4] = *(const float4*)(e1 + h*1024 + r*32 + c4);
        if (tid < 32) e2s[tid] = e2[h*1024 + rn*32 + tid];
    }
    __syncthreads();

    // phase 1: contract over rm
    {
        float4 acc = make_float4(0.f,0.f,0.f,0.f);
        const float* vcol = vbh + cm*HD_ + dq*4;
        #pragma unroll 8
        for (int rm = 0; rm < 32; ++rm) {
            float4 vv = *(const float4*)(vcol + (size_t)rm*32*HD_);
            float wgt = e2s[rm];
            acc.x = fmaf(wgt, vv.x, acc.x);
            acc.y = fmaf(wgt, vv.y, acc.y);
            acc.z = fmaf(wgt, vv.z, acc.z);
            acc.w = fmaf(wgt, vv.w, acc.w);
        }
        *(float4*)&t1[cm][dq*4] = acc;
    }
    if (tid < 32) {     // mask channel: cm = tid
        float s = 0.f;
        for (int rm = 0; rm < 32; ++rm)
            s = fmaf(e2s[rm], mb[rm*32 + tid], s);
        t1m[tid] = s;
    }
    __syncthreads();

    // phase 2: contract over cm (cn = same index var as cm mapping)
    const size_t bh = (size_t)b*NH_ + h;
    {
        const int cn = cm;
        float4 acc = make_float4(0.f,0.f,0.f,0.f);
        #pragma unroll 8
        for (int ci = 0; ci < 32; ++ci) {
            float wgt = e1s[cn][ci];
            float4 tv = *(const float4*)&t1[ci][dq*4];
            acc.x = fmaf(wgt, tv.x, acc.x);
            acc.y = fmaf(wgt, tv.y, acc.y);
            acc.z = fmaf(wgt, tv.z, acc.z);
            acc.w = fmaf(wgt, tv.w, acc.w);
        }
        int n = rn*32 + cn;
        *(float4*)(a2 + (bh*N_ + n)*A2S + dq*4) = acc;
    }
    if (tid < 32) {     // mask channel out: cn = tid
        float s = 0.f;
        for (int ci = 0; ci < 32; ++ci)
            s = fmaf(e1s[tid][ci], t1m[ci], s);
        a2[(bh*N_ + rn*32 + tid)*A2S + 32] = s;
    }
}

// ---------------------------------------------------------------------------
// Kernel 4: MFMA patch attention + combine (unchanged).
// ---------------------------------------------------------------------------
__global__ __launch_bounds__(256, 4) void k_attn_mfma(
    const __hip_bfloat16* __restrict__ qbf, const __hip_bfloat16* __restrict__ kbf,
    const __hip_bfloat16* __restrict__ vt, const float* __restrict__ mask,
    const float* __restrict__ a2, const float* __restrict__ se1,
    const float* __restrict__ se2, const float* __restrict__ gating,
    float* __restrict__ ob)
{
    const int h = blockIdx.y, b = blockIdx.z;
    const int tid = threadIdx.x;
    const int w = tid >> 6, L = tid & 63;
    const int lo = L & 15, g = L >> 4;
    const int n0 = blockIdx.x * 64 + w * 16;
    const size_t bh = (size_t)b*NH_ + h;
    const __hip_bfloat16* qh = qbf + bh*(size_t)N_*HD_;
    const __hip_bfloat16* kh = kbf + bh*(size_t)N_*HD_;
    const __hip_bfloat16* vh = vt  + bh*(size_t)HD_*N_;
    const float* mb = mask + (size_t)b*N_;

    __shared__ __hip_bfloat16 plds_all[4][16*40];
    __hip_bfloat16* plds = plds_all[w];

    bf16x8 qf = *(const bf16x8*)(qh + (size_t)(n0 + lo)*HD_ + 8*g);

    const __hip_bfloat16* kbase = kh + lo*HD_ + 8*g;
    const __hip_bfloat16* vbase = vh + (size_t)lo*N_ + 8*g;

    const f32x4 Z = {0.f, 0.f, 0.f, 0.f};
    f32x4 O0 = Z, O1 = Z;
    float zs[4] = {0.f,0.f,0.f,0.f}, z1[4] = {0.f,0.f,0.f,0.f};
    const float SC = 0.1767766952966369f;   // 1/sqrt(32)

    bf16x8 kfa = *(const bf16x8*)(kbase);
    bf16x8 kfb = *(const bf16x8*)(kbase + 16*HD_);
    bf16x8 vfa = *(const bf16x8*)(vbase);
    bf16x8 vfb = *(const bf16x8*)(vbase + 16*N_);
    float ma0 = mb[lo], ma1 = mb[lo + 16];

    for (int mt = 0; mt < 32; ++mt) {
        f32x4 s0 = MFMA16(qf, kfa, Z);
        f32x4 s1 = MFMA16(qf, kfb, Z);
        const int m1 = (mt < 31 ? mt + 1 : mt) * 32;
        bf16x8 nka = *(const bf16x8*)(kbase + (size_t)m1*HD_);
        bf16x8 nkb = *(const bf16x8*)(kbase + (size_t)m1*HD_ + 16*HD_);
        bf16x8 nva = *(const bf16x8*)(vbase + m1);
        bf16x8 nvb = *(const bf16x8*)(vbase + m1 + 16*N_);
        float nm0 = mb[m1 + lo], nm1 = mb[m1 + lo + 16];
        #pragma unroll
        for (int j = 0; j < 4; ++j) {
            float e0  = __expf(s0[j] * SC);
            float e1v = __expf(s1[j] * SC);
            zs[j] += e0 + e1v;
            float p0 = e0 * ma0, p1 = e1v * ma1;
            z1[j] += p0 + p1;
            int r = 4*g + j;
            plds[r*40 + lo]      = __float2bfloat16(p0);
            plds[r*40 + 16 + lo] = __float2bfloat16(p1);
        }
        bf16x8 pa = *(const bf16x8*)(plds + lo*40 + 8*g);
        O0 = MFMA16(pa, vfa, O0);
        O1 = MFMA16(pa, vfb, O1);
        kfa = nka; kfb = nkb; vfa = nva; vfb = nvb; ma0 = nm0; ma1 = nm1;
    }

    const float gs = 1.f / (1.f + __expf(-gating[h]));
    #pragma unroll
    for (int j = 0; j < 4; ++j) {
        float tzs = zs[j], tz1 = z1[j];
        #pragma unroll
        for (int msk = 1; msk < 16; msk <<= 1) {
            tzs += __shfl_xor(tzs, msk);
            tz1 += __shfl_xor(tz1, msk);
        }
        const int n = n0 + 4*g + j;
        const float* a2p = a2 + (bh*N_ + n)*A2S;
        float z2m = a2p[32];
        float zp  = se1[h*32 + (n & 31)] * se2[h*32 + (n >> 5)];
        float w1  = (1.f - gs) / tzs;
        float w2  = gs / zp;
        float inv = 1.f / (w1*tz1 + w2*z2m);
        float o0 = (w1*O0[j] + w2*a2p[lo])      * inv;
        float o1 = (w1*O1[j] + w2*a2p[16 + lo]) * inv;
        float* op = ob + ((size_t)b*N_ + n)*C_ + h*HD_;
        op[lo]      = o0;
        op[16 + lo] = o1;
    }
}

// ---------------------------------------------------------------------------
// Kernel 5: output projection + bias, transposed write to (B,C,N).
// ---------------------------------------------------------------------------
__global__ __launch_bounds__(256) void k_proj(
    const float* __restrict__ ob, const float* __restrict__ Wp,
    const float* __restrict__ bp, float* __restrict__ out)
{
    const int ct = blockIdx.x, nt = blockIdx.y, b = blockIdx.z;
    const int cb = ct*64, nb = nt*64;
    const int tid = threadIdx.x;
    const int tx = tid & 15, ty = tid >> 4;
    __shared__ float os[64][33];
    __shared__ float wt[64][33];
    float acc[4][4] = {};

    for (int c0 = 0; c0 < C_; c0 += 32) {
        int rl = tid >> 2;
        int cl = (tid & 3) * 8;
        {
            const float* src = ob + ((size_t)b*N_ + nb + rl)*C_ + c0 + cl;
            float4 v0 = ((const float4*)src)[0];
            float4 v1 = ((const float4*)src)[1];
            os[rl][cl+0]=v0.x; os[rl][cl+1]=v0.y; os[rl][cl+2]=v0.z; os[rl][cl+3]=v0.w;
            os[rl][cl+4]=v1.x; os[rl][cl+5]=v1.y; os[rl][cl+6]=v1.z; os[rl][cl+7]=v1.w;
            const float* wsrc = Wp + (size_t)(cb + rl)*C_ + c0 + cl;
            float4 w0 = ((const float4*)wsrc)[0];
            float4 w1 = ((const float4*)wsrc)[1];
            wt[rl][cl+0]=w0.x; wt[rl][cl+1]=w0.y; wt[rl][cl+2]=w0.z; wt[rl][cl+3]=w0.w;
            wt[rl][cl+4]=w1.x; wt[rl][cl+5]=w1.y; wt[rl][cl+6]=w1.z; wt[rl][cl+7]=w1.w;
        }
        __syncthreads();
        #pragma unroll
        for (int c2 = 0; c2 < 32; ++c2) {
            float ov[4], wv[4];
            #pragma unroll
            for (int ni = 0; ni < 4; ++ni) ov[ni] = os[tx*4+ni][c2];
            #pragma unroll
            for (int cj = 0; cj < 4; ++cj) wv[cj] = wt[ty*4+cj][c2];
            #pragma unroll
            for (int cj = 0; cj < 4; ++cj)
                #pragma unroll
                for (int ni = 0; ni < 4; ++ni)
                    acc[cj][ni] = fmaf(wv[cj], ov[ni], acc[cj][ni]);
        }
        __syncthreads();
    }

    #pragma unroll
    for (int cj = 0; cj < 4; ++cj) {
        float bv = bp[cb + ty*4 + cj];
        #pragma unroll
        for (int ni = 0; ni < 4; ++ni)
            out[((size_t)b*C_ + cb + ty*4 + cj)*N_ + nb + tx*4 + ni] = acc[cj][ni] + bv;
    }
}

// ---------------------------------------------------------------------------
extern "C" void kernel_launch(void* const* d_in, const int* in_sizes, int n_in,
                              void* d_out, int out_size, void* d_ws, size_t ws_size,
                              hipStream_t stream)
{
    (void)in_sizes; (void)n_in; (void)out_size; (void)ws_size;
    const float* x      = (const float*)d_in[0];
    const float* mask   = (const float*)d_in[1];
    const float* Wqk    = (const float*)d_in[2];
    const float* Wv     = (const float*)d_in[3];
    const float* Wproj  = (const float*)d_in[4];
    const float* bproj  = (const float*)d_in[5];
    const float* Wpos   = (const float*)d_in[6];
    const float* bpos   = (const float*)d_in[7];
    const float* gating = (const float*)d_in[8];
    float* out = (float*)d_out;
    char* w = (char*)d_ws;

    float*          vbuf = (float*)(w + OFF_VB);
    __hip_bfloat16* qbf  = (__hip_bfloat16*)(w + OFF_QBF);
    __hip_bfloat16* kbf  = (__hip_bfloat16*)(w + OFF_KBF);
    __hip_bfloat16* vt   = (__hip_bfloat16*)(w + OFF_VT);
    float*          e1   = (float*)(w + OFF_E1);
    float*          e2   = (float*)(w + OFF_E2);
    float*          se1  = (float*)(w + OFF_SE1);
    float*          se2  = (float*)(w + OFF_SE2);
    float*          a2   = (float*)(w + OFF_A2);
    float*          obuf = (float*)(w + OFF_O);

    k_qkv<<<dim3(12,16,8), dim3(256), 0, stream>>>(x, Wqk, Wv, qbf, kbf, vt, vbuf);
    k_pos_tables<<<dim3(8), dim3(1024), 0, stream>>>(Wpos, bpos, e1, e2, se1, se2);
    k_pos_apply<<<dim3(32,8,8), dim3(256), 0, stream>>>(vbuf, mask, e1, e2, a2);
    k_attn_mfma<<<dim3(16,8,8), dim3(256), 0, stream>>>(qbf, kbf, vt, mask, a2, se1, se2, gating, obuf);
    k_proj<<<dim3(4,16,8), dim3(256), 0, stream>>>(obuf, Wproj, bproj, out);
}

// Round 4
// 125.601 us; speedup vs baseline: 5.2100x; 1.1895x over previous
//
#include <hip/hip_runtime.h>
#include <hip/hip_bf16.h>
#include <math.h>

#define B_ 8
#define C_ 256
#define N_ 1024
#define NH_ 8
#define HD_ 32

typedef __attribute__((ext_vector_type(8))) short bf16x8;
typedef __attribute__((ext_vector_type(4))) short bf16x4;
typedef __attribute__((ext_vector_type(4))) float f32x4;
#define MFMA16(a,b,c) __builtin_amdgcn_mfma_f32_16x16x32_bf16((a),(b),(c),0,0,0)

static __device__ __forceinline__ short f2bf(float f) {
    __hip_bfloat16 h = __float2bfloat16(f);
    return *reinterpret_cast<short*>(&h);
}

// ---- workspace byte offsets -------------------------------------------------
static constexpr size_t OFF_VB   = 0;                        // fp32 V [b,h,n,d]   8 MB
static constexpr size_t OFF_QBF  = 8388608;                  // bf16 Q [b,h,n,d]   4 MB
static constexpr size_t OFF_KBF  = 12582912;                 // bf16 K [b,h,n,d]   4 MB
static constexpr size_t OFF_VT   = 16777216;                 // bf16 V^T [b,h,d,n] 4 MB
static constexpr size_t OFF_E1   = 20971520;
static constexpr size_t OFF_E2   = 21004288;
static constexpr size_t OFF_SE1  = 21037056;
static constexpr size_t OFF_SE2  = 21038080;
static constexpr size_t OFF_A2   = 21039104;                 // fp32 [b,h,n,36] 9.4 MB
static constexpr size_t A2S      = 36;
static constexpr size_t OFF_O    = 30476288;                 // bf16 obf [b,n,c] 4 MB; ALIASED xbf (disjoint lifetime)
static constexpr size_t OFF_WBF  = 34670592;                 // bf16 [768][256] 384 KB
static constexpr size_t OFF_WPBF = 35063808;                 // bf16 [256][256] 128 KB
// end = 35,194,880 bytes (< 38.9 MB used previously)

// ---------------------------------------------------------------------------
// Kernel 0: one-shot weight conversion fp32 -> bf16.
// rows 0..511 = Wqk, 512..767 = Wv (-> wbf), 768..1023 = Wproj (-> wpbf)
// ---------------------------------------------------------------------------
__global__ __launch_bounds__(256) void k_w_cvt(
    const float* __restrict__ Wqk, const float* __restrict__ Wv,
    const float* __restrict__ Wp, __hip_bfloat16* __restrict__ wbf,
    __hip_bfloat16* __restrict__ wpbf)
{
    int idx = blockIdx.x * 256 + threadIdx.x;        // 0..65535
    int row = idx >> 6;
    int c4  = (idx & 63) * 4;
    const float* src = (row < 512) ? (Wqk + (size_t)row*256)
                     : (row < 768) ? (Wv + (size_t)(row-512)*256)
                                   : (Wp + (size_t)(row-768)*256);
    float4 v = *(const float4*)(src + c4);
    bf16x4 pk;
    pk[0] = f2bf(v.x); pk[1] = f2bf(v.y); pk[2] = f2bf(v.z); pk[3] = f2bf(v.w);
    __hip_bfloat16* dst = (row < 768) ? (wbf + (size_t)row*256)
                                      : (wpbf + (size_t)(row-768)*256);
    *(bf16x4*)(dst + c4) = pk;
}

// ---------------------------------------------------------------------------
// Kernel 0b: transpose x (B,C,N) fp32 -> xbf (B,N,C) bf16 via LDS tiles.
// ---------------------------------------------------------------------------
__global__ __launch_bounds__(256) void k_xT(
    const float* __restrict__ x, __hip_bfloat16* __restrict__ xbf)
{
    const int n0 = blockIdx.x * 64, c0 = blockIdx.y * 64, b = blockIdx.z;
    __shared__ float tile[64][68];
    const int t = threadIdx.x;
    {
        int cl = t >> 2, nq = (t & 3) * 16;
        const float* src = x + ((size_t)b*C_ + c0 + cl)*N_ + n0 + nq;
        #pragma unroll
        for (int i = 0; i < 4; ++i)
            *(float4*)&tile[cl][nq + i*4] = ((const float4*)src)[i];
    }
    __syncthreads();
    {
        int nl = t >> 2, cq = (t & 3) * 16;
        short pk[16];
        #pragma unroll
        for (int i = 0; i < 16; ++i) pk[i] = f2bf(tile[cq + i][nl]);
        __hip_bfloat16* dst = xbf + ((size_t)b*N_ + n0 + nl)*C_ + c0 + cq;
        *(uint4*)dst       = *(uint4*)&pk[0];
        *(uint4*)(dst + 8) = *(uint4*)&pk[8];
    }
}

// ---------------------------------------------------------------------------
// Kernel 1: QKV projection on MFMA.  D[j][n] = sum_c W[j][c] * x[n][c].
// A = wbf rows (16 j), B = xbf cols (16 n), K = 256 (8 steps).  No LDS.
// Wave = 16 j x 64 n. Block = 64 j x 64 n. Epilogue scatters q/k/v.
// ---------------------------------------------------------------------------
__global__ __launch_bounds__(256) void k_qkv_mfma(
    const __hip_bfloat16* __restrict__ xbf, const __hip_bfloat16* __restrict__ wbf,
    __hip_bfloat16* __restrict__ qbf, __hip_bfloat16* __restrict__ kbf,
    __hip_bfloat16* __restrict__ vt, float* __restrict__ vbuf)
{
    const int t = threadIdx.x, w = t >> 6, L = t & 63, lo = L & 15, g = L >> 4;
    const int jw = blockIdx.x * 64 + w * 16;
    const int n0 = blockIdx.y * 64, b = blockIdx.z;

    const __hip_bfloat16* arow = wbf + (size_t)(jw + lo)*256 + 8*g;
    bf16x8 af[8];
    #pragma unroll
    for (int ks = 0; ks < 8; ++ks) af[ks] = *(const bf16x8*)(arow + ks*32);

    const f32x4 Z = {0.f,0.f,0.f,0.f};
    f32x4 D0 = Z, D1 = Z, D2 = Z, D3 = Z;
    const __hip_bfloat16* xb = xbf + ((size_t)b*N_ + n0 + lo)*256 + 8*g;
    #pragma unroll
    for (int ks = 0; ks < 8; ++ks) {
        bf16x8 b0 = *(const bf16x8*)(xb + ks*32);
        bf16x8 b1 = *(const bf16x8*)(xb + 16*256 + ks*32);
        bf16x8 b2 = *(const bf16x8*)(xb + 32*256 + ks*32);
        bf16x8 b3 = *(const bf16x8*)(xb + 48*256 + ks*32);
        D0 = MFMA16(af[ks], b0, D0);
        D1 = MFMA16(af[ks], b1, D1);
        D2 = MFMA16(af[ks], b2, D2);
        D3 = MFMA16(af[ks], b3, D3);
    }
    f32x4 D[4] = {D0, D1, D2, D3};

    const size_t bb = (size_t)b*NH_;
    if (jw < 512) {
        __hip_bfloat16* dst = (jw < 256) ? qbf : kbf;
        int j2 = jw & 255, h = j2 >> 5, d0 = (j2 & 31) + 4*g;
        #pragma unroll
        for (int nt = 0; nt < 4; ++nt) {
            int nn = n0 + nt*16 + lo;
            bf16x4 pk;
            #pragma unroll
            for (int r = 0; r < 4; ++r) pk[r] = f2bf(D[nt][r]);
            *(bf16x4*)(dst + ((bb + h)*N_ + nn)*HD_ + d0) = pk;
        }
    } else {
        int j2 = jw - 512, h = j2 >> 5, d0 = (j2 & 31) + 4*g;
        #pragma unroll
        for (int nt = 0; nt < 4; ++nt) {
            int nn = n0 + nt*16 + lo;
            float4 fv = make_float4(D[nt][0], D[nt][1], D[nt][2], D[nt][3]);
            *(float4*)(vbuf + ((bb + h)*N_ + nn)*HD_ + d0) = fv;
            #pragma unroll
            for (int r = 0; r < 4; ++r)
                vt[((bb + h)*HD_ + d0 + r)*N_ + nn] = __float2bfloat16(D[nt][r]);
        }
    }
}

// ---------------------------------------------------------------------------
// Kernel 2: positional factor tables per head (separable exp factors).
// ---------------------------------------------------------------------------
__global__ __launch_bounds__(1024) void k_pos_tables(
    const float* __restrict__ Wpos, const float* __restrict__ bpos,
    float* __restrict__ e1, float* __restrict__ e2,
    float* __restrict__ se1, float* __restrict__ se2)
{
    const int h = blockIdx.x;
    const int tid = threadIdx.x;
    const int i = tid >> 5, j = tid & 31;
    const float wx = Wpos[h*3+0], wy = Wpos[h*3+1], wd = Wpos[h*3+2], bp = bpos[h];
    __shared__ float sh[2][32][33];
    float fmx = -1e30f, gmx = -1e30f;
    for (int jp = 0; jp < 32; ++jp) {
        float dx = (float)(jp - i);
        float q2 = wd*dx*dx;
        fmx = fmaxf(fmx, wx*dx + q2 + bp);
        gmx = fmaxf(gmx, wy*dx + q2);
    }
    float dx = (float)(j - i);
    float q2 = wd*dx*dx;
    float fv = __expf(wx*dx + q2 + bp - fmx);
    float gv = __expf(wy*dx + q2 - gmx);
    e1[h*1024 + i*32 + j] = fv;
    e2[h*1024 + i*32 + j] = gv;
    sh[0][i][j] = fv; sh[1][i][j] = gv;
    __syncthreads();
    if (tid < 32) {
        float s1 = 0.f, s2 = 0.f;
        for (int jp = 0; jp < 32; ++jp) { s1 += sh[0][tid][jp]; s2 += sh[1][tid][jp]; }
        se1[h*32+tid] = s1; se2[h*32+tid] = s2;
    }
}

// ---------------------------------------------------------------------------
// Kernel 3: positional attention @ V, fused two-phase per block.
// ---------------------------------------------------------------------------
__global__ __launch_bounds__(256) void k_pos_apply(
    const float* __restrict__ vb, const float* __restrict__ mask,
    const float* __restrict__ e1, const float* __restrict__ e2,
    float* __restrict__ a2)
{
    const int rn = blockIdx.x, h = blockIdx.y, b = blockIdx.z;
    const int tid = threadIdx.x;
    const int cm = tid >> 3, dq = tid & 7;
    __shared__ float t1[32][36];
    __shared__ float e1s[32][36];
    __shared__ float t1m[32];
    __shared__ float e2s[32];
    const float* vbh = vb + (((size_t)b*NH_ + h)*N_)*HD_;
    const float* mb  = mask + (size_t)b*N_;

    {
        int r = tid >> 3, c4 = (tid & 7) * 4;
        *(float4*)&e1s[r][c4] = *(const float4*)(e1 + h*1024 + r*32 + c4);
        if (tid < 32) e2s[tid] = e2[h*1024 + rn*32 + tid];
    }
    __syncthreads();

    {
        float4 acc = make_float4(0.f,0.f,0.f,0.f);
        const float* vcol = vbh + cm*HD_ + dq*4;
        #pragma unroll 8
        for (int rm = 0; rm < 32; ++rm) {
            float4 vv = *(const float4*)(vcol + (size_t)rm*32*HD_);
            float wgt = e2s[rm];
            acc.x = fmaf(wgt, vv.x, acc.x);
            acc.y = fmaf(wgt, vv.y, acc.y);
            acc.z = fmaf(wgt, vv.z, acc.z);
            acc.w = fmaf(wgt, vv.w, acc.w);
        }
        *(float4*)&t1[cm][dq*4] = acc;
    }
    if (tid < 32) {
        float s = 0.f;
        for (int rm = 0; rm < 32; ++rm)
            s = fmaf(e2s[rm], mb[rm*32 + tid], s);
        t1m[tid] = s;
    }
    __syncthreads();

    const size_t bh = (size_t)b*NH_ + h;
    {
        const int cn = cm;
        float4 acc = make_float4(0.f,0.f,0.f,0.f);
        #pragma unroll 8
        for (int ci = 0; ci < 32; ++ci) {
            float wgt = e1s[cn][ci];
            float4 tv = *(const float4*)&t1[ci][dq*4];
            acc.x = fmaf(wgt, tv.x, acc.x);
            acc.y = fmaf(wgt, tv.y, acc.y);
            acc.z = fmaf(wgt, tv.z, acc.z);
            acc.w = fmaf(wgt, tv.w, acc.w);
        }
        int n = rn*32 + cn;
        *(float4*)(a2 + (bh*N_ + n)*A2S + dq*4) = acc;
    }
    if (tid < 32) {
        float s = 0.f;
        for (int ci = 0; ci < 32; ++ci)
            s = fmaf(e1s[tid][ci], t1m[ci], s);
        a2[(bh*N_ + rn*32 + tid)*A2S + 32] = s;
    }
}

// ---------------------------------------------------------------------------
// Kernel 4: MFMA patch attention + combine -> bf16 obf.
// ---------------------------------------------------------------------------
__global__ __launch_bounds__(256, 4) void k_attn_mfma(
    const __hip_bfloat16* __restrict__ qbf, const __hip_bfloat16* __restrict__ kbf,
    const __hip_bfloat16* __restrict__ vt, const float* __restrict__ mask,
    const float* __restrict__ a2, const float* __restrict__ se1,
    const float* __restrict__ se2, const float* __restrict__ gating,
    __hip_bfloat16* __restrict__ ob)
{
    const int h = blockIdx.y, b = blockIdx.z;
    const int tid = threadIdx.x;
    const int w = tid >> 6, L = tid & 63;
    const int lo = L & 15, g = L >> 4;
    const int n0 = blockIdx.x * 64 + w * 16;
    const size_t bh = (size_t)b*NH_ + h;
    const __hip_bfloat16* qh = qbf + bh*(size_t)N_*HD_;
    const __hip_bfloat16* kh = kbf + bh*(size_t)N_*HD_;
    const __hip_bfloat16* vh = vt  + bh*(size_t)HD_*N_;
    const float* mb = mask + (size_t)b*N_;

    __shared__ __hip_bfloat16 plds_all[4][16*40];
    __hip_bfloat16* plds = plds_all[w];

    bf16x8 qf = *(const bf16x8*)(qh + (size_t)(n0 + lo)*HD_ + 8*g);

    const __hip_bfloat16* kbase = kh + lo*HD_ + 8*g;
    const __hip_bfloat16* vbase = vh + (size_t)lo*N_ + 8*g;

    const f32x4 Z = {0.f, 0.f, 0.f, 0.f};
    f32x4 O0 = Z, O1 = Z;
    float zs[4] = {0.f,0.f,0.f,0.f}, z1[4] = {0.f,0.f,0.f,0.f};
    const float SC = 0.1767766952966369f;   // 1/sqrt(32)

    bf16x8 kfa = *(const bf16x8*)(kbase);
    bf16x8 kfb = *(const bf16x8*)(kbase + 16*HD_);
    bf16x8 vfa = *(const bf16x8*)(vbase);
    bf16x8 vfb = *(const bf16x8*)(vbase + 16*N_);
    float ma0 = mb[lo], ma1 = mb[lo + 16];

    for (int mt = 0; mt < 32; ++mt) {
        f32x4 s0 = MFMA16(qf, kfa, Z);
        f32x4 s1 = MFMA16(qf, kfb, Z);
        const int m1 = (mt < 31 ? mt + 1 : mt) * 32;
        bf16x8 nka = *(const bf16x8*)(kbase + (size_t)m1*HD_);
        bf16x8 nkb = *(const bf16x8*)(kbase + (size_t)m1*HD_ + 16*HD_);
        bf16x8 nva = *(const bf16x8*)(vbase + m1);
        bf16x8 nvb = *(const bf16x8*)(vbase + m1 + 16*N_);
        float nm0 = mb[m1 + lo], nm1 = mb[m1 + lo + 16];
        #pragma unroll
        for (int j = 0; j < 4; ++j) {
            float e0  = __expf(s0[j] * SC);
            float e1v = __expf(s1[j] * SC);
            zs[j] += e0 + e1v;
            float p0 = e0 * ma0, p1 = e1v * ma1;
            z1[j] += p0 + p1;
            int r = 4*g + j;
            plds[r*40 + lo]      = __float2bfloat16(p0);
            plds[r*40 + 16 + lo] = __float2bfloat16(p1);
        }
        bf16x8 pa = *(const bf16x8*)(plds + lo*40 + 8*g);
        O0 = MFMA16(pa, vfa, O0);
        O1 = MFMA16(pa, vfb, O1);
        kfa = nka; kfb = nkb; vfa = nva; vfb = nvb; ma0 = nm0; ma1 = nm1;
    }

    const float gs = 1.f / (1.f + __expf(-gating[h]));
    #pragma unroll
    for (int j = 0; j < 4; ++j) {
        float tzs = zs[j], tz1 = z1[j];
        #pragma unroll
        for (int msk = 1; msk < 16; msk <<= 1) {
            tzs += __shfl_xor(tzs, msk);
            tz1 += __shfl_xor(tz1, msk);
        }
        const int n = n0 + 4*g + j;
        const float* a2p = a2 + (bh*N_ + n)*A2S;
        float z2m = a2p[32];
        float zp  = se1[h*32 + (n & 31)] * se2[h*32 + (n >> 5)];
        float w1  = (1.f - gs) / tzs;
        float w2  = gs / zp;
        float inv = 1.f / (w1*tz1 + w2*z2m);
        float o0 = (w1*O0[j] + w2*a2p[lo])      * inv;
        float o1 = (w1*O1[j] + w2*a2p[16 + lo]) * inv;
        __hip_bfloat16* op = ob + ((size_t)b*N_ + n)*C_ + h*HD_;
        op[lo]      = __float2bfloat16(o0);
        op[16 + lo] = __float2bfloat16(o1);
    }
}

// ---------------------------------------------------------------------------
// Kernel 5: output projection on MFMA.  out[c][n] = sum_k Wp[c][k]*obf[n][k].
// A = wpbf rows (16 c), B = obf cols (16 n). No LDS. Bias + transposed write.
// ---------------------------------------------------------------------------
__global__ __launch_bounds__(256) void k_proj_mfma(
    const __hip_bfloat16* __restrict__ obf, const __hip_bfloat16* __restrict__ wpbf,
    const float* __restrict__ bp, float* __restrict__ out)
{
    const int t = threadIdx.x, w = t >> 6, L = t & 63, lo = L & 15, g = L >> 4;
    const int cw = blockIdx.x * 64 + w * 16;
    const int n0 = blockIdx.y * 64, b = blockIdx.z;

    const __hip_bfloat16* arow = wpbf + (size_t)(cw + lo)*256 + 8*g;
    bf16x8 af[8];
    #pragma unroll
    for (int ks = 0; ks < 8; ++ks) af[ks] = *(const bf16x8*)(arow + ks*32);

    const f32x4 Z = {0.f,0.f,0.f,0.f};
    f32x4 D0 = Z, D1 = Z, D2 = Z, D3 = Z;
    const __hip_bfloat16* xb = obf + ((size_t)b*N_ + n0 + lo)*256 + 8*g;
    #pragma unroll
    for (int ks = 0; ks < 8; ++ks) {
        bf16x8 b0 = *(const bf16x8*)(xb + ks*32);
        bf16x8 b1 = *(const bf16x8*)(xb + 16*256 + ks*32);
        bf16x8 b2 = *(const bf16x8*)(xb + 32*256 + ks*32);
        bf16x8 b3 = *(const bf16x8*)(xb + 48*256 + ks*32);
        D0 = MFMA16(af[ks], b0, D0);
        D1 = MFMA16(af[ks], b1, D1);
        D2 = MFMA16(af[ks], b2, D2);
        D3 = MFMA16(af[ks], b3, D3);
    }
    f32x4 D[4] = {D0, D1, D2, D3};

    float bias[4];
    #pragma unroll
    for (int r = 0; r < 4; ++r) bias[r] = bp[cw + 4*g + r];
    #pragma unroll
    for (int nt = 0; nt < 4; ++nt) {
        int nn = n0 + nt*16 + lo;
        #pragma unroll
        for (int r = 0; r < 4; ++r)
            out[((size_t)b*C_ + cw + 4*g + r)*N_ + nn] = D[nt][r] + bias[r];
    }
}

// ---------------------------------------------------------------------------
extern "C" void kernel_launch(void* const* d_in, const int* in_sizes, int n_in,
                              void* d_out, int out_size, void* d_ws, size_t ws_size,
                              hipStream_t stream)
{
    (void)in_sizes; (void)n_in; (void)out_size; (void)ws_size;
    const float* x      = (const float*)d_in[0];
    const float* mask   = (const float*)d_in[1];
    const float* Wqk    = (const float*)d_in[2];
    const float* Wv     = (const float*)d_in[3];
    const float* Wproj  = (const float*)d_in[4];
    const float* bproj  = (const float*)d_in[5];
    const float* Wpos   = (const float*)d_in[6];
    const float* bpos   = (const float*)d_in[7];
    const float* gating = (const float*)d_in[8];
    float* out = (float*)d_out;
    char* w = (char*)d_ws;

    float*          vbuf = (float*)(w + OFF_VB);
    __hip_bfloat16* qbf  = (__hip_bfloat16*)(w + OFF_QBF);
    __hip_bfloat16* kbf  = (__hip_bfloat16*)(w + OFF_KBF);
    __hip_bfloat16* vt   = (__hip_bfloat16*)(w + OFF_VT);
    float*          e1   = (float*)(w + OFF_E1);
    float*          e2   = (float*)(w + OFF_E2);
    float*          se1  = (float*)(w + OFF_SE1);
    float*          se2  = (float*)(w + OFF_SE2);
    float*          a2   = (float*)(w + OFF_A2);
    __hip_bfloat16* obf  = (__hip_bfloat16*)(w + OFF_O);
    __hip_bfloat16* xbf  = (__hip_bfloat16*)(w + OFF_O);    // alias: lifetime disjoint from obf
    __hip_bfloat16* wbf  = (__hip_bfloat16*)(w + OFF_WBF);
    __hip_bfloat16* wpbf = (__hip_bfloat16*)(w + OFF_WPBF);

    k_w_cvt<<<dim3(256), dim3(256), 0, stream>>>(Wqk, Wv, Wproj, wbf, wpbf);
    k_xT<<<dim3(16,4,8), dim3(256), 0, stream>>>(x, xbf);
    k_pos_tables<<<dim3(8), dim3(1024), 0, stream>>>(Wpos, bpos, e1, e2, se1, se2);
    k_qkv_mfma<<<dim3(12,16,8), dim3(256), 0, stream>>>(xbf, wbf, qbf, kbf, vt, vbuf);
    k_pos_apply<<<dim3(32,8,8), dim3(256), 0, stream>>>(vbuf, mask, e1, e2, a2);
    k_attn_mfma<<<dim3(16,8,8), dim3(256), 0, stream>>>(qbf, kbf, vt, mask, a2, se1, se2, gating, obf);
    k_proj_mfma<<<dim3(4,16,8), dim3(256), 0, stream>>>(obf, wpbf, bproj, out);
}

// Round 5
// 120.201 us; speedup vs baseline: 5.4441x; 1.0449x over previous
//
#include <hip/hip_runtime.h>
#include <hip/hip_bf16.h>
#include <math.h>

#define B_ 8
#define C_ 256
#define N_ 1024
#define NH_ 8
#define HD_ 32

typedef __attribute__((ext_vector_type(8))) short bf16x8;
typedef __attribute__((ext_vector_type(4))) short bf16x4;
typedef __attribute__((ext_vector_type(4))) float f32x4;
typedef __attribute__((ext_vector_type(16))) float f32x16;
typedef __attribute__((ext_vector_type(2))) unsigned int u32x2;
typedef __attribute__((ext_vector_type(4))) unsigned int u32x4;
#define MFMA16(a,b,c) __builtin_amdgcn_mfma_f32_16x16x32_bf16((a),(b),(c),0,0,0)
#define MFMA32(a,b,c) __builtin_amdgcn_mfma_f32_32x32x16_bf16((a),(b),(c),0,0,0)

static __device__ __forceinline__ short f2bf(float f) {
    __hip_bfloat16 h = __float2bfloat16(f);
    return *reinterpret_cast<short*>(&h);
}
static __device__ __forceinline__ unsigned int cvtpk(float a, float b) {
    unsigned int r;
    asm("v_cvt_pk_bf16_f32 %0, %1, %2" : "=v"(r) : "v"(a), "v"(b));
    return r;
}

// folded scale for Q: (1/sqrt(32)) * log2(e)
#define FS 0.2550352584f

// ---- workspace byte offsets -------------------------------------------------
static constexpr size_t OFF_VB   = 0;                        // fp32 V [b,h,n,d]   8 MB
static constexpr size_t OFF_QBF  = 8388608;                  // bf16 Q [b,h,n,d]   4 MB (pre-scaled by FS)
static constexpr size_t OFF_KBF  = 12582912;                 // bf16 K [b,h,n,d]   4 MB
static constexpr size_t OFF_VT   = 16777216;                 // bf16 V^T*mask [b,h,d,n] 4 MB
static constexpr size_t OFF_E1   = 20971520;
static constexpr size_t OFF_E2   = 21004288;
static constexpr size_t OFF_SE1  = 21037056;
static constexpr size_t OFF_SE2  = 21038080;
static constexpr size_t OFF_A2   = 21039104;                 // fp32 [b,h,n,36] 9.4 MB
static constexpr size_t A2S      = 36;
static constexpr size_t OFF_O    = 30476288;                 // bf16 obf [b,n,c] 4 MB; ALIASED xbf
static constexpr size_t OFF_WBF  = 34670592;                 // bf16 [768][256] 384 KB
static constexpr size_t OFF_WPBF = 35063808;                 // bf16 [256][256] 128 KB
static constexpr size_t OFF_ZVT  = 35194880;                 // bf16 [b][32][1024] 512 KB (c0=mask,c1=ones)
// end = 35,719,168 bytes

// ---------------------------------------------------------------------------
// Kernel 0: one-shot weight conversion fp32 -> bf16.
// ---------------------------------------------------------------------------
__global__ __launch_bounds__(256) void k_w_cvt(
    const float* __restrict__ Wqk, const float* __restrict__ Wv,
    const float* __restrict__ Wp, __hip_bfloat16* __restrict__ wbf,
    __hip_bfloat16* __restrict__ wpbf)
{
    int idx = blockIdx.x * 256 + threadIdx.x;
    int row = idx >> 6;
    int c4  = (idx & 63) * 4;
    const float* src = (row < 512) ? (Wqk + (size_t)row*256)
                     : (row < 768) ? (Wv + (size_t)(row-512)*256)
                                   : (Wp + (size_t)(row-768)*256);
    float4 v = *(const float4*)(src + c4);
    bf16x4 pk;
    pk[0] = f2bf(v.x); pk[1] = f2bf(v.y); pk[2] = f2bf(v.z); pk[3] = f2bf(v.w);
    __hip_bfloat16* dst = (row < 768) ? (wbf + (size_t)row*256)
                                      : (wpbf + (size_t)(row-768)*256);
    *(bf16x4*)(dst + c4) = pk;
}

// ---------------------------------------------------------------------------
// Kernel 0b: transpose x (B,C,N) fp32 -> xbf (B,N,C) bf16 via LDS tiles.
// ---------------------------------------------------------------------------
__global__ __launch_bounds__(256) void k_xT(
    const float* __restrict__ x, __hip_bfloat16* __restrict__ xbf)
{
    const int n0 = blockIdx.x * 64, c0 = blockIdx.y * 64, b = blockIdx.z;
    __shared__ float tile[64][68];
    const int t = threadIdx.x;
    {
        int cl = t >> 2, nq = (t & 3) * 16;
        const float* src = x + ((size_t)b*C_ + c0 + cl)*N_ + n0 + nq;
        #pragma unroll
        for (int i = 0; i < 4; ++i)
            *(float4*)&tile[cl][nq + i*4] = ((const float4*)src)[i];
    }
    __syncthreads();
    {
        int nl = t >> 2, cq = (t & 3) * 16;
        short pk[16];
        #pragma unroll
        for (int i = 0; i < 16; ++i) pk[i] = f2bf(tile[cq + i][nl]);
        __hip_bfloat16* dst = xbf + ((size_t)b*N_ + n0 + nl)*C_ + c0 + cq;
        *(uint4*)dst       = *(uint4*)&pk[0];
        *(uint4*)(dst + 8) = *(uint4*)&pk[8];
    }
}

// ---------------------------------------------------------------------------
// Kernel 0c: build zvt[b][32][1024]: row0 = mask (bf16), row1 = 1.0, rest 0.
// ---------------------------------------------------------------------------
__global__ __launch_bounds__(256) void k_zvt(
    const float* __restrict__ mask, __hip_bfloat16* __restrict__ zvt)
{
    int idx = blockIdx.x * 256 + threadIdx.x;    // 32768 threads, 8 bf16 each
    int m8  = (idx & 127) * 8;
    int row = (idx >> 7) & 31;
    int b   = idx >> 12;
    bf16x8 v;
    if (row == 0) {
        const float* mp = mask + (size_t)b*N_ + m8;
        #pragma unroll
        for (int i = 0; i < 8; ++i) v[i] = f2bf(mp[i]);
    } else {
        short c = (row == 1) ? (short)0x3F80 : (short)0;
        #pragma unroll
        for (int i = 0; i < 8; ++i) v[i] = c;
    }
    *(bf16x8*)(zvt + ((size_t)b*32 + row)*N_ + m8) = v;
}

// ---------------------------------------------------------------------------
// Kernel 1: QKV projection on MFMA.  Q pre-scaled by FS; V^T masked.
// ---------------------------------------------------------------------------
__global__ __launch_bounds__(256) void k_qkv_mfma(
    const __hip_bfloat16* __restrict__ xbf, const __hip_bfloat16* __restrict__ wbf,
    const float* __restrict__ mask,
    __hip_bfloat16* __restrict__ qbf, __hip_bfloat16* __restrict__ kbf,
    __hip_bfloat16* __restrict__ vt, float* __restrict__ vbuf)
{
    const int t = threadIdx.x, w = t >> 6, L = t & 63, lo = L & 15, g = L >> 4;
    const int jw = blockIdx.x * 64 + w * 16;
    const int n0 = blockIdx.y * 64, b = blockIdx.z;

    const __hip_bfloat16* arow = wbf + (size_t)(jw + lo)*256 + 8*g;
    bf16x8 af[8];
    #pragma unroll
    for (int ks = 0; ks < 8; ++ks) af[ks] = *(const bf16x8*)(arow + ks*32);

    const f32x4 Z = {0.f,0.f,0.f,0.f};
    f32x4 D0 = Z, D1 = Z, D2 = Z, D3 = Z;
    const __hip_bfloat16* xb = xbf + ((size_t)b*N_ + n0 + lo)*256 + 8*g;
    #pragma unroll
    for (int ks = 0; ks < 8; ++ks) {
        bf16x8 b0 = *(const bf16x8*)(xb + ks*32);
        bf16x8 b1 = *(const bf16x8*)(xb + 16*256 + ks*32);
        bf16x8 b2 = *(const bf16x8*)(xb + 32*256 + ks*32);
        bf16x8 b3 = *(const bf16x8*)(xb + 48*256 + ks*32);
        D0 = MFMA16(af[ks], b0, D0);
        D1 = MFMA16(af[ks], b1, D1);
        D2 = MFMA16(af[ks], b2, D2);
        D3 = MFMA16(af[ks], b3, D3);
    }
    f32x4 D[4] = {D0, D1, D2, D3};

    const size_t bb = (size_t)b*NH_;
    if (jw < 512) {
        const bool isq = (jw < 256);
        __hip_bfloat16* dst = isq ? qbf : kbf;
        int j2 = jw & 255, h = j2 >> 5, d0 = (j2 & 31) + 4*g;
        float sc = isq ? FS : 1.f;
        #pragma unroll
        for (int nt = 0; nt < 4; ++nt) {
            int nn = n0 + nt*16 + lo;
            bf16x4 pk;
            #pragma unroll
            for (int r = 0; r < 4; ++r) pk[r] = f2bf(D[nt][r] * sc);
            *(bf16x4*)(dst + ((bb + h)*N_ + nn)*HD_ + d0) = pk;
        }
    } else {
        int j2 = jw - 512, h = j2 >> 5, d0 = (j2 & 31) + 4*g;
        #pragma unroll
        for (int nt = 0; nt < 4; ++nt) {
            int nn = n0 + nt*16 + lo;
            float mval = mask[(size_t)b*N_ + nn];
            float4 fv = make_float4(D[nt][0], D[nt][1], D[nt][2], D[nt][3]);
            *(float4*)(vbuf + ((bb + h)*N_ + nn)*HD_ + d0) = fv;
            #pragma unroll
            for (int r = 0; r < 4; ++r)
                vt[((bb + h)*HD_ + d0 + r)*N_ + nn] = __float2bfloat16(D[nt][r] * mval);
        }
    }
}

// ---------------------------------------------------------------------------
// Kernel 2: positional factor tables per head (separable exp factors).
// ---------------------------------------------------------------------------
__global__ __launch_bounds__(1024) void k_pos_tables(
    const float* __restrict__ Wpos, const float* __restrict__ bpos,
    float* __restrict__ e1, float* __restrict__ e2,
    float* __restrict__ se1, float* __restrict__ se2)
{
    const int h = blockIdx.x;
    const int tid = threadIdx.x;
    const int i = tid >> 5, j = tid & 31;
    const float wx = Wpos[h*3+0], wy = Wpos[h*3+1], wd = Wpos[h*3+2], bp = bpos[h];
    __shared__ float sh[2][32][33];
    float fmx = -1e30f, gmx = -1e30f;
    for (int jp = 0; jp < 32; ++jp) {
        float dx = (float)(jp - i);
        float q2 = wd*dx*dx;
        fmx = fmaxf(fmx, wx*dx + q2 + bp);
        gmx = fmaxf(gmx, wy*dx + q2);
    }
    float dx = (float)(j - i);
    float q2 = wd*dx*dx;
    float fv = __expf(wx*dx + q2 + bp - fmx);
    float gv = __expf(wy*dx + q2 - gmx);
    e1[h*1024 + i*32 + j] = fv;
    e2[h*1024 + i*32 + j] = gv;
    sh[0][i][j] = fv; sh[1][i][j] = gv;
    __syncthreads();
    if (tid < 32) {
        float s1 = 0.f, s2 = 0.f;
        for (int jp = 0; jp < 32; ++jp) { s1 += sh[0][tid][jp]; s2 += sh[1][tid][jp]; }
        se1[h*32+tid] = s1; se2[h*32+tid] = s2;
    }
}

// ---------------------------------------------------------------------------
// Kernel 3: positional attention @ V, fused two-phase per block.
// ---------------------------------------------------------------------------
__global__ __launch_bounds__(256) void k_pos_apply(
    const float* __restrict__ vb, const float* __restrict__ mask,
    const float* __restrict__ e1, const float* __restrict__ e2,
    float* __restrict__ a2)
{
    const int rn = blockIdx.x, h = blockIdx.y, b = blockIdx.z;
    const int tid = threadIdx.x;
    const int cm = tid >> 3, dq = tid & 7;
    __shared__ float t1[32][36];
    __shared__ float e1s[32][36];
    __shared__ float t1m[32];
    __shared__ float e2s[32];
    const float* vbh = vb + (((size_t)b*NH_ + h)*N_)*HD_;
    const float* mb  = mask + (size_t)b*N_;

    {
        int r = tid >> 3, c4 = (tid & 7) * 4;
        *(float4*)&e1s[r][c4] = *(const float4*)(e1 + h*1024 + r*32 + c4);
        if (tid < 32) e2s[tid] = e2[h*1024 + rn*32 + tid];
    }
    __syncthreads();

    {
        float4 acc = make_float4(0.f,0.f,0.f,0.f);
        const float* vcol = vbh + cm*HD_ + dq*4;
        #pragma unroll 8
        for (int rm = 0; rm < 32; ++rm) {
            float4 vv = *(const float4*)(vcol + (size_t)rm*32*HD_);
            float wgt = e2s[rm];
            acc.x = fmaf(wgt, vv.x, acc.x);
            acc.y = fmaf(wgt, vv.y, acc.y);
            acc.z = fmaf(wgt, vv.z, acc.z);
            acc.w = fmaf(wgt, vv.w, acc.w);
        }
        *(float4*)&t1[cm][dq*4] = acc;
    }
    if (tid < 32) {
        float s = 0.f;
        for (int rm = 0; rm < 32; ++rm)
            s = fmaf(e2s[rm], mb[rm*32 + tid], s);
        t1m[tid] = s;
    }
    __syncthreads();

    const size_t bh = (size_t)b*NH_ + h;
    {
        const int cn = cm;
        float4 acc = make_float4(0.f,0.f,0.f,0.f);
        #pragma unroll 8
        for (int ci = 0; ci < 32; ++ci) {
            float wgt = e1s[cn][ci];
            float4 tv = *(const float4*)&t1[ci][dq*4];
            acc.x = fmaf(wgt, tv.x, acc.x);
            acc.y = fmaf(wgt, tv.y, acc.y);
            acc.z = fmaf(wgt, tv.z, acc.z);
            acc.w = fmaf(wgt, tv.w, acc.w);
        }
        int n = rn*32 + cn;
        *(float4*)(a2 + (bh*N_ + n)*A2S + dq*4) = acc;
    }
    if (tid < 32) {
        float s = 0.f;
        for (int ci = 0; ci < 32; ++ci)
            s = fmaf(e1s[tid][ci], t1m[ci], s);
        a2[(bh*N_ + rn*32 + tid)*A2S + 32] = s;
    }
}

// ---------------------------------------------------------------------------
// Kernel 4: attention, swapped-QK^T 32x32 MFMA, softmax fully in-register.
// Lane holds S^T col (its own Q-row) -> exp2 in regs -> cvt_pk+permlane32_swap
// builds PV A-fragments -> PV + Z (mask/ones channels) MFMAs. Zero LDS.
// ---------------------------------------------------------------------------
__global__ __launch_bounds__(256, 2) void k_attn_mfma(
    const __hip_bfloat16* __restrict__ qbf, const __hip_bfloat16* __restrict__ kbf,
    const __hip_bfloat16* __restrict__ vt, const __hip_bfloat16* __restrict__ zvt,
    const float* __restrict__ a2, const float* __restrict__ se1,
    const float* __restrict__ se2, const float* __restrict__ gating,
    __hip_bfloat16* __restrict__ ob)
{
    const int t = threadIdx.x, w = t >> 6, L = t & 63;
    const int ln = L & 31, hi = L >> 5;
    const int h = blockIdx.y, b = blockIdx.z;
    const int n0 = blockIdx.x * 128 + w * 32;
    const size_t bh = (size_t)b*NH_ + h;
    const __hip_bfloat16* qh = qbf + bh*(size_t)N_*HD_;
    const __hip_bfloat16* kh = kbf + bh*(size_t)N_*HD_;
    const __hip_bfloat16* vh = vt  + bh*(size_t)HD_*N_;
    const __hip_bfloat16* zh = zvt + (size_t)b*32*N_;

    // Q B-fragments (fixed for whole loop): B[k][col=n] = Q[n0+ln][k]
    bf16x8 qf0 = *(const bf16x8*)(qh + (size_t)(n0 + ln)*HD_ + 8*hi);
    bf16x8 qf1 = *(const bf16x8*)(qh + (size_t)(n0 + ln)*HD_ + 16 + 8*hi);

    const __hip_bfloat16* kb = kh + (size_t)ln*HD_ + 8*hi;      // + m0*HD_
    const __hip_bfloat16* vb = vh + (size_t)ln*N_ + 8*hi;       // + m0
    const __hip_bfloat16* zb = zh + (size_t)ln*N_ + 8*hi;       // + m0

    f32x16 O = {0.f}; f32x16 Zc = {0.f};
    #pragma unroll
    for (int i = 0; i < 16; ++i) { O[i] = 0.f; Zc[i] = 0.f; }

    bf16x8 ka0 = *(const bf16x8*)(kb);
    bf16x8 ka1 = *(const bf16x8*)(kb + 16);
    bf16x8 vf0 = *(const bf16x8*)(vb);
    bf16x8 vf1 = *(const bf16x8*)(vb + 16);
    bf16x8 zf0 = *(const bf16x8*)(zb);
    bf16x8 zf1 = *(const bf16x8*)(zb + 16);

    for (int mt = 0; mt < 32; ++mt) {
        // S^T[m][n]: A = K rows (m), B = Q cols (n); accumulate over d-chunks
        f32x16 S;
        #pragma unroll
        for (int i = 0; i < 16; ++i) S[i] = 0.f;
        S = MFMA32(ka0, qf0, S);
        S = MFMA32(ka1, qf1, S);

        const int m1 = (mt < 31 ? mt + 1 : mt) * 32;
        bf16x8 nka0 = *(const bf16x8*)(kb + (size_t)m1*HD_);
        bf16x8 nka1 = *(const bf16x8*)(kb + (size_t)m1*HD_ + 16);
        bf16x8 nvf0 = *(const bf16x8*)(vb + m1);
        bf16x8 nvf1 = *(const bf16x8*)(vb + m1 + 16);
        bf16x8 nzf0 = *(const bf16x8*)(zb + m1);
        bf16x8 nzf1 = *(const bf16x8*)(zb + m1 + 16);

        float e[16];
        #pragma unroll
        for (int i = 0; i < 16; ++i) e[i] = exp2f(S[i]);

        // chunk 0 (m-local 0..15) from e[0..7]
        unsigned int x01 = cvtpk(e[0], e[1]), x23 = cvtpk(e[2], e[3]);
        unsigned int x45 = cvtpk(e[4], e[5]), x67 = cvtpk(e[6], e[7]);
        u32x2 r02 = __builtin_amdgcn_permlane32_swap(x01, x45, false, false);
        u32x2 r13 = __builtin_amdgcn_permlane32_swap(x23, x67, false, false);
        u32x4 p0u = { r02[0], r13[0], r02[1], r13[1] };
        bf16x8 pa0 = *reinterpret_cast<bf16x8*>(&p0u);
        // chunk 1 (m-local 16..31) from e[8..15]
        unsigned int y01 = cvtpk(e[8], e[9]),  y23 = cvtpk(e[10], e[11]);
        unsigned int y45 = cvtpk(e[12], e[13]), y67 = cvtpk(e[14], e[15]);
        u32x2 s02 = __builtin_amdgcn_permlane32_swap(y01, y45, false, false);
        u32x2 s13 = __builtin_amdgcn_permlane32_swap(y23, y67, false, false);
        u32x4 p1u = { s02[0], s13[0], s02[1], s13[1] };
        bf16x8 pa1 = *reinterpret_cast<bf16x8*>(&p1u);

        O  = MFMA32(pa0, vf0, O);
        O  = MFMA32(pa1, vf1, O);
        Zc = MFMA32(pa0, zf0, Zc);
        Zc = MFMA32(pa1, zf1, Zc);

        ka0 = nka0; ka1 = nka1; vf0 = nvf0; vf1 = nvf1; zf0 = nzf0; zf1 = nzf1;
    }

    const float gs = 1.f / (1.f + __expf(-gating[h]));
    #pragma unroll
    for (int r = 0; r < 16; ++r) {
        const int n = n0 + (r&3) + 8*(r>>2) + 4*hi;
        float z1m = __shfl(Zc[r], (L & 32) | 0);
        float zsv = __shfl(Zc[r], (L & 32) | 1);
        const float* a2p = a2 + (bh*N_ + n)*A2S;
        float z2m = a2p[32];
        float zp  = se1[h*32 + (n & 31)] * se2[h*32 + (n >> 5)];
        float w1  = (1.f - gs) / zsv;
        float w2  = gs / zp;
        float inv = 1.f / (w1*z1m + w2*z2m);
        float o = (w1*O[r] + w2*a2p[ln]) * inv;
        ob[((size_t)b*N_ + n)*C_ + h*HD_ + ln] = __float2bfloat16(o);
    }
}

// ---------------------------------------------------------------------------
// Kernel 5: output projection on MFMA.
// ---------------------------------------------------------------------------
__global__ __launch_bounds__(256) void k_proj_mfma(
    const __hip_bfloat16* __restrict__ obf, const __hip_bfloat16* __restrict__ wpbf,
    const float* __restrict__ bp, float* __restrict__ out)
{
    const int t = threadIdx.x, w = t >> 6, L = t & 63, lo = L & 15, g = L >> 4;
    const int cw = blockIdx.x * 64 + w * 16;
    const int n0 = blockIdx.y * 64, b = blockIdx.z;

    const __hip_bfloat16* arow = wpbf + (size_t)(cw + lo)*256 + 8*g;
    bf16x8 af[8];
    #pragma unroll
    for (int ks = 0; ks < 8; ++ks) af[ks] = *(const bf16x8*)(arow + ks*32);

    const f32x4 Z = {0.f,0.f,0.f,0.f};
    f32x4 D0 = Z, D1 = Z, D2 = Z, D3 = Z;
    const __hip_bfloat16* xb = obf + ((size_t)b*N_ + n0 + lo)*256 + 8*g;
    #pragma unroll
    for (int ks = 0; ks < 8; ++ks) {
        bf16x8 b0 = *(const bf16x8*)(xb + ks*32);
        bf16x8 b1 = *(const bf16x8*)(xb + 16*256 + ks*32);
        bf16x8 b2 = *(const bf16x8*)(xb + 32*256 + ks*32);
        bf16x8 b3 = *(const bf16x8*)(xb + 48*256 + ks*32);
        D0 = MFMA16(af[ks], b0, D0);
        D1 = MFMA16(af[ks], b1, D1);
        D2 = MFMA16(af[ks], b2, D2);
        D3 = MFMA16(af[ks], b3, D3);
    }
    f32x4 D[4] = {D0, D1, D2, D3};

    float bias[4];
    #pragma unroll
    for (int r = 0; r < 4; ++r) bias[r] = bp[cw + 4*g + r];
    #pragma unroll
    for (int nt = 0; nt < 4; ++nt) {
        int nn = n0 + nt*16 + lo;
        #pragma unroll
        for (int r = 0; r < 4; ++r)
            out[((size_t)b*C_ + cw + 4*g + r)*N_ + nn] = D[nt][r] + bias[r];
    }
}

// ---------------------------------------------------------------------------
extern "C" void kernel_launch(void* const* d_in, const int* in_sizes, int n_in,
                              void* d_out, int out_size, void* d_ws, size_t ws_size,
                              hipStream_t stream)
{
    (void)in_sizes; (void)n_in; (void)out_size; (void)ws_size;
    const float* x      = (const float*)d_in[0];
    const float* mask   = (const float*)d_in[1];
    const float* Wqk    = (const float*)d_in[2];
    const float* Wv     = (const float*)d_in[3];
    const float* Wproj  = (const float*)d_in[4];
    const float* bproj  = (const float*)d_in[5];
    const float* Wpos   = (const float*)d_in[6];
    const float* bpos   = (const float*)d_in[7];
    const float* gating = (const float*)d_in[8];
    float* out = (float*)d_out;
    char* w = (char*)d_ws;

    float*          vbuf = (float*)(w + OFF_VB);
    __hip_bfloat16* qbf  = (__hip_bfloat16*)(w + OFF_QBF);
    __hip_bfloat16* kbf  = (__hip_bfloat16*)(w + OFF_KBF);
    __hip_bfloat16* vt   = (__hip_bfloat16*)(w + OFF_VT);
    float*          e1   = (float*)(w + OFF_E1);
    float*          e2   = (float*)(w + OFF_E2);
    float*          se1  = (float*)(w + OFF_SE1);
    float*          se2  = (float*)(w + OFF_SE2);
    float*          a2   = (float*)(w + OFF_A2);
    __hip_bfloat16* obf  = (__hip_bfloat16*)(w + OFF_O);
    __hip_bfloat16* xbf  = (__hip_bfloat16*)(w + OFF_O);    // alias: lifetime disjoint
    __hip_bfloat16* wbf  = (__hip_bfloat16*)(w + OFF_WBF);
    __hip_bfloat16* wpbf = (__hip_bfloat16*)(w + OFF_WPBF);
    __hip_bfloat16* zvt  = (__hip_bfloat16*)(w + OFF_ZVT);

    k_w_cvt<<<dim3(256), dim3(256), 0, stream>>>(Wqk, Wv, Wproj, wbf, wpbf);
    k_xT<<<dim3(16,4,8), dim3(256), 0, stream>>>(x, xbf);
    k_zvt<<<dim3(128), dim3(256), 0, stream>>>(mask, zvt);
    k_pos_tables<<<dim3(8), dim3(1024), 0, stream>>>(Wpos, bpos, e1, e2, se1, se2);
    k_qkv_mfma<<<dim3(12,16,8), dim3(256), 0, stream>>>(xbf, wbf, mask, qbf, kbf, vt, vbuf);
    k_pos_apply<<<dim3(32,8,8), dim3(256), 0, stream>>>(vbuf, mask, e1, e2, a2);
    k_attn_mfma<<<dim3(8,8,8), dim3(256), 0, stream>>>(qbf, kbf, vt, zvt, a2, se1, se2, gating, obf);
    k_proj_mfma<<<dim3(4,16,8), dim3(256), 0, stream>>>(obf, wpbf, bproj, out);
}